// Round 3
// baseline (2467.057 us; speedup 1.0000x reference)
//
#include <hip/hip_runtime.h>

// GAT 2-layer, N=100000 nodes, E=1.6M edges, dims 128->64->64, all fp32.
// Strategy:
//   - s[i] = a[i]·we collapses edge-logit GEMV to per-node scalar (We is [1,64]).
//   - tanh-bounded logits => skip segment_max (exp ratio identical).
//   - NO fine CSR (16x write-amp on scatter). Coarse 128-node bins instead:
//     one-kernel LDS counting sort into fixed-capacity bin regions (packed
//     dst<<7|src&127), then one block per bin aggregates via LDS fp32 atomics
//     (order-within-bin agnostic). Fuses edge weights, softmax denom, weighted
//     aggregate, std(ddof=1) normalize.
//   - k_node: W staged in 32KB LDS chunks (3 blocks/CU) + 2-deep software
//     pipeline on broadcast x loads to cover ~900cyc HBM latency.

#define WS_ALIGN 256
#define BIN_SHIFT 7
#define BIN_NODES 128
#define BIN_CAP 2560   // mean bin count 2048, sigma ~44 -> +11.6 sigma margin
#define MAX_BINS 1024
#define EPB 4096       // edges per k_bin block

__device__ __forceinline__ float wave_sum(float x) {
#pragma unroll
  for (int m = 32; m > 0; m >>= 1) x += __shfl_xor(x, m, 64);
  return x;
}

__device__ __forceinline__ float fast_tanh(float x) {
  x = fminf(15.f, fmaxf(-15.f, x));
  float e = __expf(2.f * x);
  return (e - 1.f) * __builtin_amdgcn_rcpf(e + 1.f);
}

__global__ void k_init_cursor(int* __restrict__ cursor, int nb) {
  int i = blockIdx.x * 256 + threadIdx.x;
  if (i < nb) cursor[i] = i * BIN_CAP;
}

// Coarse counting-sort of edges into 128-node bins. 4096 edges staged in LDS,
// per-block LDS histogram, ONE global atomic per (block,bin), packed 4B writes
// in ~5-entry runs per bin per block (~3x line amp vs 16x for fine scatter).
__global__ __launch_bounds__(256) void k_bin(const int* __restrict__ src,
                                             const int* __restrict__ dst,
                                             int* __restrict__ cursor,
                                             int* __restrict__ binned, int E, int nb) {
  __shared__ int ssrc[EPB];
  __shared__ int sdst[EPB];
  __shared__ int hist[MAX_BINS];
  __shared__ int base[MAX_BINS];
  int t = threadIdx.x;
  for (int i = t; i < nb; i += 256) hist[i] = 0;
  __syncthreads();
  int e0 = blockIdx.x * EPB;
  for (int i = t; i < EPB; i += 256) {
    int e = e0 + i;
    int sv = -1, dv = 0;
    if (e < E) {
      sv = src[e];
      dv = dst[e];
      atomicAdd(&hist[sv >> BIN_SHIFT], 1);
    }
    ssrc[i] = sv;
    sdst[i] = dv;
  }
  __syncthreads();
  for (int b = t; b < nb; b += 256) {
    int c = hist[b];
    base[b] = c ? atomicAdd(&cursor[b], c) : 0;
    hist[b] = 0;
  }
  __syncthreads();
  for (int i = t; i < EPB; i += 256) {
    int sv = ssrc[i];
    if (sv >= 0) {
      int b = sv >> BIN_SHIFT;
      int r = atomicAdd(&hist[b], 1);
      int pos = base[b] + r;
      if (pos < (b + 1) * BIN_CAP)  // overflow guard (never expected to fire)
        binned[pos] = (sdst[i] << BIN_SHIFT) | (sv & (BIN_NODES - 1));
    }
  }
}

// Fused per-node kernel: v = tanh(x@Wv^T+bv) -> [N,64]; s = tanh(x@Wa^T+ba)·we -> [N].
// 4 waves/block, 8 nodes/wave (lane = output dim). W staged in LDS in K=64 chunks
// (32KB -> 3 blocks/CU); x broadcast loads software-pipelined 2 deep.
// Requires n % 32 == 0 (true: 100000 = 3125*32).
template <int K>
__global__ __launch_bounds__(256, 3) void k_node(
    const float* __restrict__ x, const float* __restrict__ Wa, const float* __restrict__ ba,
    const float* __restrict__ we, const float* __restrict__ Wv, const float* __restrict__ bv,
    float* __restrict__ v_out, float* __restrict__ s_out, int n) {
  constexpr int KB = K / 4;    // float4 per row
  constexpr int CH = K / 64;   // K-chunks of 64
  constexpr int KBC = KB / CH; // 16 float4 per chunk
  __shared__ float4 sWa[64 * KBC];  // 16KB
  __shared__ float4 sWv[64 * KBC];  // 16KB
  const float4* Wa4 = (const float4*)Wa;
  const float4* Wv4 = (const float4*)Wv;
  int t = threadIdx.x;
  int l = t & 63;
  int w = t >> 6;
  int node0 = blockIdx.x * 32 + w * 8;
  const float4* xr = (const float4*)x + (size_t)node0 * KB;

  float acc_a[8], acc_v[8];
#pragma unroll
  for (int i = 0; i < 8; i++) { acc_a[i] = 0.f; acc_v[i] = 0.f; }

  for (int ch = 0; ch < CH; ch++) {
    if (ch) __syncthreads();
    for (int f = t; f < 64 * KBC; f += 256) {
      int o = f / KBC, j = f - o * KBC;
      sWa[j * 64 + o] = Wa4[o * KB + ch * KBC + j];
      sWv[j * 64 + o] = Wv4[o * KB + ch * KBC + j];
    }
    __syncthreads();
    const float4* xc = xr + ch * KBC;
    float4 xb0[8], xb1[8];
#pragma unroll
    for (int i = 0; i < 8; i++) xb0[i] = xc[(size_t)i * KB + 0];
#pragma unroll
    for (int i = 0; i < 8; i++) xb1[i] = xc[(size_t)i * KB + 1];
#pragma unroll
    for (int j2 = 0; j2 < KBC; j2 += 2) {
      {
        float4 wa = sWa[j2 * 64 + l], wv = sWv[j2 * 64 + l];
#pragma unroll
        for (int i = 0; i < 8; i++) {
          float4 xv = xb0[i];
          acc_a[i] = fmaf(xv.x, wa.x, fmaf(xv.y, wa.y, fmaf(xv.z, wa.z, fmaf(xv.w, wa.w, acc_a[i]))));
          acc_v[i] = fmaf(xv.x, wv.x, fmaf(xv.y, wv.y, fmaf(xv.z, wv.z, fmaf(xv.w, wv.w, acc_v[i]))));
        }
        if (j2 + 2 < KBC) {
#pragma unroll
          for (int i = 0; i < 8; i++) xb0[i] = xc[(size_t)i * KB + j2 + 2];
        }
      }
      {
        float4 wa = sWa[(j2 + 1) * 64 + l], wv = sWv[(j2 + 1) * 64 + l];
#pragma unroll
        for (int i = 0; i < 8; i++) {
          float4 xv = xb1[i];
          acc_a[i] = fmaf(xv.x, wa.x, fmaf(xv.y, wa.y, fmaf(xv.z, wa.z, fmaf(xv.w, wa.w, acc_a[i]))));
          acc_v[i] = fmaf(xv.x, wv.x, fmaf(xv.y, wv.y, fmaf(xv.z, wv.z, fmaf(xv.w, wv.w, acc_v[i]))));
        }
        if (j2 + 3 < KBC) {
#pragma unroll
          for (int i = 0; i < 8; i++) xb1[i] = xc[(size_t)i * KB + j2 + 3];
        }
      }
    }
  }

  float bal = ba[l], bvl = bv[l], wel = we[l];
#pragma unroll
  for (int i = 0; i < 8; i++) {
    int node = node0 + i;
    float a = fast_tanh(acc_a[i] + bal);
    float vv = fast_tanh(acc_v[i] + bvl);
    v_out[(size_t)node * 64 + l] = vv;
    float sv = wave_sum(a * wel);
    if (l == 0) s_out[node] = sv;
  }
}

// One block per 128-node bin. LDS fp32-atomic accumulators; edge weights
// computed in-kernel; v-row gathers 8-deep per wave for MLP. Finalizes
// softmax-normalize + std(ddof=1) and writes out coalesced.
__global__ __launch_bounds__(256, 4) void k_aggr_bin(
    const int* __restrict__ binned, const int* __restrict__ cursor,
    const float* __restrict__ s, const float* __restrict__ be_p,
    const float* __restrict__ v, float* __restrict__ out, int n) {
  __shared__ float acc[BIN_NODES * 64];  // 32KB
  __shared__ float den[BIN_NODES];
  __shared__ float sloc[BIN_NODES];
  int bin = blockIdx.x;
  int nbase = bin << BIN_SHIFT;
  int nn = min(BIN_NODES, n - nbase);
  int t = threadIdx.x;
  for (int i = t; i < BIN_NODES * 64; i += 256) acc[i] = 0.f;
  if (t < BIN_NODES) {
    den[t] = 0.f;
    sloc[t] = (t < nn) ? s[nbase + t] : 0.f;
  }
  __syncthreads();
  int cnt = cursor[bin] - bin * BIN_CAP;
  if (cnt > BIN_CAP) cnt = BIN_CAP;
  int w = t >> 6, l = t & 63;
  const int* bp = binned + (size_t)bin * BIN_CAP;
  float be = be_p[0];

  int idx = w;  // 4 waves, stride 4, unroll 8 -> step 32
  for (; idx + 28 < cnt; idx += 32) {
    int pk[8], sl[8];
    float vr[8], wt[8];
#pragma unroll
    for (int u = 0; u < 8; u++) pk[u] = bp[idx + u * 4];
#pragma unroll
    for (int u = 0; u < 8; u++) {
      int d = pk[u] >> BIN_SHIFT;
      sl[u] = pk[u] & (BIN_NODES - 1);
      vr[u] = v[(size_t)d * 64 + l];
      wt[u] = __expf(fast_tanh(sloc[sl[u]] + s[d] + be));
    }
#pragma unroll
    for (int u = 0; u < 8; u++) {
      atomicAdd(&acc[sl[u] * 64 + l], wt[u] * vr[u]);
      if (l == 0) atomicAdd(&den[sl[u]], wt[u]);
    }
  }
  for (; idx < cnt; idx += 4) {
    int pk = bp[idx];
    int d = pk >> BIN_SHIFT;
    int sl0 = pk & (BIN_NODES - 1);
    float vr = v[(size_t)d * 64 + l];
    float wt = __expf(fast_tanh(sloc[sl0] + s[d] + be));
    atomicAdd(&acc[sl0 * 64 + l], wt * vr);
    if (l == 0) atomicAdd(&den[sl0], wt);
  }
  __syncthreads();

  for (int j = w; j < nn; j += 4) {
    float o = acc[j * 64 + l] / den[j];
    float sum = wave_sum(o);
    float sumsq = wave_sum(o * o);
    float var = (sumsq - sum * sum * (1.0f / 64.f)) * (1.0f / 63.f);
    out[(size_t)(nbase + j) * 64 + l] = o / sqrtf(var);
  }
}

extern "C" void kernel_launch(void* const* d_in, const int* in_sizes, int n_in,
                              void* d_out, int out_size, void* d_ws, size_t ws_size,
                              hipStream_t stream) {
  const float* h = (const float*)d_in[0];
  const int* ei = (const int*)d_in[1];
  const float* W11 = (const float*)d_in[2];
  const float* b11 = (const float*)d_in[3];
  const float* W12 = (const float*)d_in[4];  // [1,64] -> 64-vec
  const float* b12 = (const float*)d_in[5];
  const float* W13 = (const float*)d_in[6];
  const float* b13 = (const float*)d_in[7];
  const float* W21 = (const float*)d_in[8];
  const float* b21 = (const float*)d_in[9];
  const float* W22 = (const float*)d_in[10];
  const float* b22 = (const float*)d_in[11];
  const float* W23 = (const float*)d_in[12];
  const float* b23 = (const float*)d_in[13];

  const int N = in_sizes[0] / 128;  // 100000
  const int E = in_sizes[1] / 2;    // 1600000
  const int* src = ei;
  const int* dst = ei + E;
  const int NB = (N + BIN_NODES - 1) >> BIN_SHIFT;  // 782

  // workspace carve-up (~60 MB)
  char* p = (char*)d_ws;
  auto alloc = [&](size_t bytes) -> void* {
    void* r = (void*)p;
    p += (bytes + WS_ALIGN - 1) / WS_ALIGN * WS_ALIGN;
    return r;
  };
  int* cursor = (int*)alloc((size_t)NB * 4);
  int* binned = (int*)alloc((size_t)NB * BIN_CAP * 4);  // 8.0MB
  float* sbuf = (float*)alloc((size_t)N * 4);
  float* vbuf = (float*)alloc((size_t)N * 64 * 4);
  float* out1 = (float*)alloc((size_t)N * 64 * 4);

  // ---- binning (reused by both layers) ----
  k_init_cursor<<<(NB + 255) / 256, 256, 0, stream>>>(cursor, NB);
  k_bin<<<(E + EPB - 1) / EPB, 256, 0, stream>>>(src, dst, cursor, binned, E, NB);

  // ---- layer 1 (K=128) ----
  k_node<128><<<(N + 31) / 32, 256, 0, stream>>>(h, W11, b11, W12, W13, b13, vbuf, sbuf, N);
  k_aggr_bin<<<NB, 256, 0, stream>>>(binned, cursor, sbuf, b12, vbuf, out1, N);

  // ---- layer 2 (K=64) ----
  k_node<64><<<(N + 31) / 32, 256, 0, stream>>>(out1, W21, b21, W22, W23, b23, vbuf, sbuf, N);
  k_aggr_bin<<<NB, 256, 0, stream>>>(binned, cursor, sbuf, b22, vbuf, (float*)d_out, N);
}

// Round 4
// 2333.205 us; speedup vs baseline: 1.0574x; 1.0574x over previous
//
#include <hip/hip_runtime.h>

// GAT 2-layer, N=100000 nodes, E=1.6M edges, dims 128->64->64, all fp32.
// Strategy:
//   - s[i] = a[i]·we collapses edge-logit GEMV to per-node scalar (We is [1,64]).
//   - tanh-bounded logits => skip segment_max (exp ratio identical).
//   - Coarse 128-node bins (no fine CSR): one-kernel LDS counting sort into
//     fixed-capacity bin regions (packed dst<<7|src&127), then one block per bin
//     aggregates via LDS fp32 atomics. Fuses edge weights, softmax denom,
//     weighted aggregate, std(ddof=1) normalize.
//   - k_node v3: x tile staged in LDS via coalesced float4 loads (NO broadcast
//     global loads, NO register prefetch buffers -> no spills). W staged per
//     64-K chunk with stride-66 padding (write 4-way, read conflict-free).
//     ~49KB LDS -> 3 blocks/CU.

#define WS_ALIGN 256
#define BIN_SHIFT 7
#define BIN_NODES 128
#define BIN_CAP 2560   // mean bin count 2048, sigma ~44 -> +11.6 sigma margin
#define MAX_BINS 1024
#define EPB 4096       // edges per k_bin block

__device__ __forceinline__ float wave_sum(float x) {
#pragma unroll
  for (int m = 32; m > 0; m >>= 1) x += __shfl_xor(x, m, 64);
  return x;
}

__device__ __forceinline__ float fast_tanh(float x) {
  x = fminf(15.f, fmaxf(-15.f, x));
  float e = __expf(2.f * x);
  return (e - 1.f) * __builtin_amdgcn_rcpf(e + 1.f);
}

__global__ void k_init_cursor(int* __restrict__ cursor, int nb) {
  int i = blockIdx.x * 256 + threadIdx.x;
  if (i < nb) cursor[i] = i * BIN_CAP;
}

// Coarse counting-sort of edges into 128-node bins. 4096 edges staged in LDS,
// per-block LDS histogram, ONE global atomic per (block,bin), packed 4B writes
// in ~5-entry runs per bin per block (~3x line amp vs 16x for fine scatter).
__global__ __launch_bounds__(256) void k_bin(const int* __restrict__ src,
                                             const int* __restrict__ dst,
                                             int* __restrict__ cursor,
                                             int* __restrict__ binned, int E, int nb) {
  __shared__ int ssrc[EPB];
  __shared__ int sdst[EPB];
  __shared__ int hist[MAX_BINS];
  __shared__ int base[MAX_BINS];
  int t = threadIdx.x;
  for (int i = t; i < nb; i += 256) hist[i] = 0;
  __syncthreads();
  int e0 = blockIdx.x * EPB;
  for (int i = t; i < EPB; i += 256) {
    int e = e0 + i;
    int sv = -1, dv = 0;
    if (e < E) {
      sv = src[e];
      dv = dst[e];
      atomicAdd(&hist[sv >> BIN_SHIFT], 1);
    }
    ssrc[i] = sv;
    sdst[i] = dv;
  }
  __syncthreads();
  for (int b = t; b < nb; b += 256) {
    int c = hist[b];
    base[b] = c ? atomicAdd(&cursor[b], c) : 0;
    hist[b] = 0;
  }
  __syncthreads();
  for (int i = t; i < EPB; i += 256) {
    int sv = ssrc[i];
    if (sv >= 0) {
      int b = sv >> BIN_SHIFT;
      int r = atomicAdd(&hist[b], 1);
      int pos = base[b] + r;
      if (pos < (b + 1) * BIN_CAP)  // overflow guard (never expected to fire)
        binned[pos] = (sdst[i] << BIN_SHIFT) | (sv & (BIN_NODES - 1));
    }
  }
}

// Fused per-node kernel: v = tanh(x@Wv^T+bv) -> [N,64]; s = tanh(x@Wa^T+ba)·we -> [N].
// 4 waves/block, 8 nodes/wave (lane = output dim). x tile (32 rows x K) staged in
// LDS once via coalesced float4 loads; W staged per 64-K chunk, stride-66 padded.
// Inner loop reads are all LDS (8 broadcast + 2 lane-spread b128 per kb).
// Requires n % 32 == 0 (true: 100000 = 3125*32).
template <int K>
__global__ __launch_bounds__(256, 3) void k_node(
    const float* __restrict__ x, const float* __restrict__ Wa, const float* __restrict__ ba,
    const float* __restrict__ we, const float* __restrict__ Wv, const float* __restrict__ bv,
    float* __restrict__ v_out, float* __restrict__ s_out, int n) {
  constexpr int KB = K / 4;   // float4 per x row
  constexpr int CH = K / 64;  // 64-wide K chunks
  __shared__ float4 sWa[16 * 66];  // [kb][o], stride 66: write 4-way, read free
  __shared__ float4 sWv[16 * 66];
  __shared__ float4 sx[32 * KB];   // 16KB (K=128) / 8KB (K=64)
  int t = threadIdx.x;
  int l = t & 63;
  int w = t >> 6;
  int node0 = blockIdx.x * 32;

  // stage x tile: 32*KB contiguous float4, perfectly coalesced
  const float4* xg = (const float4*)x + (size_t)node0 * KB;
#pragma unroll
  for (int i = 0; i < 32 * KB / 256; i++) sx[i * 256 + t] = xg[i * 256 + t];

  const float4* Wa4 = (const float4*)Wa;
  const float4* Wv4 = (const float4*)Wv;

  float acc_a[8], acc_v[8];
#pragma unroll
  for (int i = 0; i < 8; i++) { acc_a[i] = 0.f; acc_v[i] = 0.f; }

  const float4* xw = &sx[(w * 8) * KB];

  for (int ch = 0; ch < CH; ch++) {
    if (ch) __syncthreads();  // protect W buffers from previous chunk's readers
    // stage W chunk: f -> o=f>>4 (out dim), kb=f&15 (K/4 within chunk); coalesced
    // global read (16 consecutive float4 per out row).
    for (int f = t; f < 1024; f += 256) {
      int o = f >> 4, kb = f & 15;
      sWa[kb * 66 + o] = Wa4[o * KB + ch * 16 + kb];
      sWv[kb * 66 + o] = Wv4[o * KB + ch * 16 + kb];
    }
    __syncthreads();  // also covers x staging on ch==0
#pragma unroll
    for (int kb = 0; kb < 16; kb++) {
      float4 wa = sWa[kb * 66 + l];
      float4 wv = sWv[kb * 66 + l];
#pragma unroll
      for (int i = 0; i < 8; i++) {
        float4 xv = xw[i * KB + ch * 16 + kb];  // broadcast ds_read_b128 (free)
        acc_a[i] = fmaf(xv.x, wa.x, fmaf(xv.y, wa.y, fmaf(xv.z, wa.z, fmaf(xv.w, wa.w, acc_a[i]))));
        acc_v[i] = fmaf(xv.x, wv.x, fmaf(xv.y, wv.y, fmaf(xv.z, wv.z, fmaf(xv.w, wv.w, acc_v[i]))));
      }
    }
  }

  float bal = ba[l], bvl = bv[l], wel = we[l];
#pragma unroll
  for (int i = 0; i < 8; i++) {
    int node = node0 + w * 8 + i;
    float a = fast_tanh(acc_a[i] + bal);
    float vv = fast_tanh(acc_v[i] + bvl);
    v_out[(size_t)node * 64 + l] = vv;
    float sv = wave_sum(a * wel);
    if (l == 0) s_out[node] = sv;
  }
}

// One block per 128-node bin. LDS fp32-atomic accumulators; edge weights
// computed in-kernel; v-row gathers 8-deep per wave for MLP. Finalizes
// softmax-normalize + std(ddof=1) and writes out coalesced.
__global__ __launch_bounds__(256, 4) void k_aggr_bin(
    const int* __restrict__ binned, const int* __restrict__ cursor,
    const float* __restrict__ s, const float* __restrict__ be_p,
    const float* __restrict__ v, float* __restrict__ out, int n) {
  __shared__ float acc[BIN_NODES * 64];  // 32KB
  __shared__ float den[BIN_NODES];
  __shared__ float sloc[BIN_NODES];
  int bin = blockIdx.x;
  int nbase = bin << BIN_SHIFT;
  int nn = min(BIN_NODES, n - nbase);
  int t = threadIdx.x;
  for (int i = t; i < BIN_NODES * 64; i += 256) acc[i] = 0.f;
  if (t < BIN_NODES) {
    den[t] = 0.f;
    sloc[t] = (t < nn) ? s[nbase + t] : 0.f;
  }
  __syncthreads();
  int cnt = cursor[bin] - bin * BIN_CAP;
  if (cnt > BIN_CAP) cnt = BIN_CAP;
  int w = t >> 6, l = t & 63;
  const int* bp = binned + (size_t)bin * BIN_CAP;
  float be = be_p[0];

  int idx = w;  // 4 waves, stride 4, unroll 8 -> step 32
  for (; idx + 28 < cnt; idx += 32) {
    int pk[8], sl[8];
    float vr[8], wt[8];
#pragma unroll
    for (int u = 0; u < 8; u++) pk[u] = bp[idx + u * 4];
#pragma unroll
    for (int u = 0; u < 8; u++) {
      int d = pk[u] >> BIN_SHIFT;
      sl[u] = pk[u] & (BIN_NODES - 1);
      vr[u] = v[(size_t)d * 64 + l];
      wt[u] = __expf(fast_tanh(sloc[sl[u]] + s[d] + be));
    }
#pragma unroll
    for (int u = 0; u < 8; u++) {
      atomicAdd(&acc[sl[u] * 64 + l], wt[u] * vr[u]);
      if (l == 0) atomicAdd(&den[sl[u]], wt[u]);
    }
  }
  for (; idx < cnt; idx += 4) {
    int pk = bp[idx];
    int d = pk >> BIN_SHIFT;
    int sl0 = pk & (BIN_NODES - 1);
    float vr = v[(size_t)d * 64 + l];
    float wt = __expf(fast_tanh(sloc[sl0] + s[d] + be));
    atomicAdd(&acc[sl0 * 64 + l], wt * vr);
    if (l == 0) atomicAdd(&den[sl0], wt);
  }
  __syncthreads();

  for (int j = w; j < nn; j += 4) {
    float o = acc[j * 64 + l] / den[j];
    float sum = wave_sum(o);
    float sumsq = wave_sum(o * o);
    float var = (sumsq - sum * sum * (1.0f / 64.f)) * (1.0f / 63.f);
    out[(size_t)(nbase + j) * 64 + l] = o / sqrtf(var);
  }
}

extern "C" void kernel_launch(void* const* d_in, const int* in_sizes, int n_in,
                              void* d_out, int out_size, void* d_ws, size_t ws_size,
                              hipStream_t stream) {
  const float* h = (const float*)d_in[0];
  const int* ei = (const int*)d_in[1];
  const float* W11 = (const float*)d_in[2];
  const float* b11 = (const float*)d_in[3];
  const float* W12 = (const float*)d_in[4];  // [1,64] -> 64-vec
  const float* b12 = (const float*)d_in[5];
  const float* W13 = (const float*)d_in[6];
  const float* b13 = (const float*)d_in[7];
  const float* W21 = (const float*)d_in[8];
  const float* b21 = (const float*)d_in[9];
  const float* W22 = (const float*)d_in[10];
  const float* b22 = (const float*)d_in[11];
  const float* W23 = (const float*)d_in[12];
  const float* b23 = (const float*)d_in[13];

  const int N = in_sizes[0] / 128;  // 100000
  const int E = in_sizes[1] / 2;    // 1600000
  const int* src = ei;
  const int* dst = ei + E;
  const int NB = (N + BIN_NODES - 1) >> BIN_SHIFT;  // 782

  // workspace carve-up (~60 MB)
  char* p = (char*)d_ws;
  auto alloc = [&](size_t bytes) -> void* {
    void* r = (void*)p;
    p += (bytes + WS_ALIGN - 1) / WS_ALIGN * WS_ALIGN;
    return r;
  };
  int* cursor = (int*)alloc((size_t)NB * 4);
  int* binned = (int*)alloc((size_t)NB * BIN_CAP * 4);  // 8.0MB
  float* sbuf = (float*)alloc((size_t)N * 4);
  float* vbuf = (float*)alloc((size_t)N * 64 * 4);
  float* out1 = (float*)alloc((size_t)N * 64 * 4);

  // ---- binning (reused by both layers) ----
  k_init_cursor<<<(NB + 255) / 256, 256, 0, stream>>>(cursor, NB);
  k_bin<<<(E + EPB - 1) / EPB, 256, 0, stream>>>(src, dst, cursor, binned, E, NB);

  // ---- layer 1 (K=128) ----
  k_node<128><<<(N + 31) / 32, 256, 0, stream>>>(h, W11, b11, W12, W13, b13, vbuf, sbuf, N);
  k_aggr_bin<<<NB, 256, 0, stream>>>(binned, cursor, sbuf, b12, vbuf, out1, N);

  // ---- layer 2 (K=64) ----
  k_node<64><<<(N + 31) / 32, 256, 0, stream>>>(out1, W21, b21, W22, W23, b23, vbuf, sbuf, N);
  k_aggr_bin<<<NB, 256, 0, stream>>>(binned, cursor, sbuf, b22, vbuf, (float*)d_out, N);
}

// Round 5
// 1023.908 us; speedup vs baseline: 2.4095x; 2.2787x over previous
//
#include <hip/hip_runtime.h>

// GAT 2-layer, N=100000 nodes, E=1.6M edges, dims 128->64->64, all fp32.
// Strategy:
//   - s[i] = a[i]·we collapses edge-logit GEMV to per-node scalar (We is [1,64]).
//   - tanh-bounded logits => skip segment_max (exp ratio identical).
//   - CSR build WITHOUT write-amplified scatter: coarse 128-node-bin counting
//     sort (k_bin, ~3x line amp on 6.4MB) then per-bin in-LDS sort (k_sort_bin)
//     with fully coalesced write-back of dst-only edges + per-node [rs,re).
//   - Aggregation: wave-per-node (100k waves of TLP), lane-parallel col+s
//     gather, shfl-broadcast weights, 8-deep v-row gathers. NO LDS atomics in
//     hot loops (they share lgkmcnt with loads -> serialization, R4 lesson).
//   - k_node: x tile + W staged in LDS (coalesced float4), all-LDS inner loop.

#define WS_ALIGN 256
#define BIN_SHIFT 7
#define BIN_NODES 128
#define BIN_CAP 2560   // mean bin count 2048, sigma ~44 -> +11.6 sigma margin
#define MAX_BINS 1024
#define EPB 4096       // edges per k_bin block

__device__ __forceinline__ float wave_sum(float x) {
#pragma unroll
  for (int m = 32; m > 0; m >>= 1) x += __shfl_xor(x, m, 64);
  return x;
}

__device__ __forceinline__ float fast_tanh(float x) {
  x = fminf(15.f, fmaxf(-15.f, x));
  float e = __expf(2.f * x);
  return (e - 1.f) * __builtin_amdgcn_rcpf(e + 1.f);
}

__global__ void k_init_cursor(int* __restrict__ cursor, int nb) {
  int i = blockIdx.x * 256 + threadIdx.x;
  if (i < nb) cursor[i] = i * BIN_CAP;
}

// Coarse counting-sort of edges into 128-node bins. 4096 edges staged in LDS,
// per-block LDS histogram, ONE global atomic per (block,bin), packed 4B writes
// in ~5-entry runs per bin per block.
__global__ __launch_bounds__(256) void k_bin(const int* __restrict__ src,
                                             const int* __restrict__ dst,
                                             int* __restrict__ cursor,
                                             int* __restrict__ binned, int E, int nb) {
  __shared__ int ssrc[EPB];
  __shared__ int sdst[EPB];
  __shared__ int hist[MAX_BINS];
  __shared__ int base[MAX_BINS];
  int t = threadIdx.x;
  for (int i = t; i < nb; i += 256) hist[i] = 0;
  __syncthreads();
  int e0 = blockIdx.x * EPB;
  for (int i = t; i < EPB; i += 256) {
    int e = e0 + i;
    int sv = -1, dv = 0;
    if (e < E) {
      sv = src[e];
      dv = dst[e];
      atomicAdd(&hist[sv >> BIN_SHIFT], 1);
    }
    ssrc[i] = sv;
    sdst[i] = dv;
  }
  __syncthreads();
  for (int b = t; b < nb; b += 256) {
    int c = hist[b];
    base[b] = c ? atomicAdd(&cursor[b], c) : 0;
    hist[b] = 0;
  }
  __syncthreads();
  for (int i = t; i < EPB; i += 256) {
    int sv = ssrc[i];
    if (sv >= 0) {
      int b = sv >> BIN_SHIFT;
      int r = atomicAdd(&hist[b], 1);
      int pos = base[b] + r;
      if (pos < (b + 1) * BIN_CAP)  // overflow guard (never expected to fire)
        binned[pos] = (sdst[i] << BIN_SHIFT) | (sv & (BIN_NODES - 1));
    }
  }
}

// One block per bin: sort the bin's edges by src-within-bin in LDS, write back
// dst-only values fully coalesced, emit per-node [rs, re).
__global__ __launch_bounds__(256) void k_sort_bin(int* __restrict__ binned,
                                                  const int* __restrict__ cursor,
                                                  int* __restrict__ rs,
                                                  int* __restrict__ re, int n) {
  __shared__ int ents[BIN_CAP];
  __shared__ int sorted[BIN_CAP];
  __shared__ int hist[BIN_NODES];
  __shared__ int scan[BIN_NODES];
  __shared__ int cur[BIN_NODES];
  int bin = blockIdx.x;
  int t = threadIdx.x;
  int nbase = bin << BIN_SHIFT;
  int cnt = cursor[bin] - bin * BIN_CAP;
  if (cnt > BIN_CAP) cnt = BIN_CAP;
  if (t < BIN_NODES) hist[t] = 0;
  __syncthreads();
  int* bp = binned + (size_t)bin * BIN_CAP;
  for (int i = t; i < cnt; i += 256) {
    int pk = bp[i];
    ents[i] = pk;
    atomicAdd(&hist[pk & (BIN_NODES - 1)], 1);
  }
  __syncthreads();
  if (t < BIN_NODES) scan[t] = hist[t];
  __syncthreads();
  for (int off = 1; off < BIN_NODES; off <<= 1) {
    int add = (t < BIN_NODES && t >= off) ? scan[t - off] : 0;
    __syncthreads();
    if (t < BIN_NODES) scan[t] += add;
    __syncthreads();
  }
  if (t < BIN_NODES) {
    int ex = scan[t] - hist[t];  // exclusive
    cur[t] = ex;
    int node = nbase + t;
    if (node < n) {
      rs[node] = bin * BIN_CAP + ex;
      re[node] = bin * BIN_CAP + ex + hist[t];
    }
  }
  __syncthreads();
  for (int i = t; i < cnt; i += 256) {
    int pk = ents[i];
    int pos = atomicAdd(&cur[pk & (BIN_NODES - 1)], 1);
    sorted[pos] = pk >> BIN_SHIFT;  // keep dst only
  }
  __syncthreads();
  for (int i = t; i < cnt; i += 256) bp[i] = sorted[i];  // coalesced write-back
}

// Fused per-node kernel: v = tanh(x@Wv^T+bv) -> [N,64]; s = tanh(x@Wa^T+ba)·we -> [N].
// 4 waves/block, 8 nodes/wave (lane = output dim). x tile (32 rows x K) staged in
// LDS once via coalesced float4 loads; W staged per 64-K chunk, stride-66 padded.
// Requires n % 32 == 0 (true: 100000 = 3125*32).
template <int K>
__global__ __launch_bounds__(256, 3) void k_node(
    const float* __restrict__ x, const float* __restrict__ Wa, const float* __restrict__ ba,
    const float* __restrict__ we, const float* __restrict__ Wv, const float* __restrict__ bv,
    float* __restrict__ v_out, float* __restrict__ s_out, int n) {
  constexpr int KB = K / 4;   // float4 per x row
  constexpr int CH = K / 64;  // 64-wide K chunks
  __shared__ float4 sWa[16 * 66];  // [kb][o], stride 66: write 4-way, read free
  __shared__ float4 sWv[16 * 66];
  __shared__ float4 sx[32 * KB];
  int t = threadIdx.x;
  int l = t & 63;
  int w = t >> 6;
  int node0 = blockIdx.x * 32;

  const float4* xg = (const float4*)x + (size_t)node0 * KB;
#pragma unroll
  for (int i = 0; i < 32 * KB / 256; i++) sx[i * 256 + t] = xg[i * 256 + t];

  const float4* Wa4 = (const float4*)Wa;
  const float4* Wv4 = (const float4*)Wv;

  float acc_a[8], acc_v[8];
#pragma unroll
  for (int i = 0; i < 8; i++) { acc_a[i] = 0.f; acc_v[i] = 0.f; }

  const float4* xw = &sx[(w * 8) * KB];

  for (int ch = 0; ch < CH; ch++) {
    if (ch) __syncthreads();
    for (int f = t; f < 1024; f += 256) {
      int o = f >> 4, kb = f & 15;
      sWa[kb * 66 + o] = Wa4[o * KB + ch * 16 + kb];
      sWv[kb * 66 + o] = Wv4[o * KB + ch * 16 + kb];
    }
    __syncthreads();
#pragma unroll
    for (int kb = 0; kb < 16; kb++) {
      float4 wa = sWa[kb * 66 + l];
      float4 wv = sWv[kb * 66 + l];
#pragma unroll
      for (int i = 0; i < 8; i++) {
        float4 xv = xw[i * KB + ch * 16 + kb];  // broadcast ds_read_b128
        acc_a[i] = fmaf(xv.x, wa.x, fmaf(xv.y, wa.y, fmaf(xv.z, wa.z, fmaf(xv.w, wa.w, acc_a[i]))));
        acc_v[i] = fmaf(xv.x, wv.x, fmaf(xv.y, wv.y, fmaf(xv.z, wv.z, fmaf(xv.w, wv.w, acc_v[i]))));
      }
    }
  }

  float bal = ba[l], bvl = bv[l], wel = we[l];
#pragma unroll
  for (int i = 0; i < 8; i++) {
    int node = node0 + w * 8 + i;
    float a = fast_tanh(acc_a[i] + bal);
    float vv = fast_tanh(acc_v[i] + bvl);
    v_out[(size_t)node * 64 + l] = vv;
    float sv = wave_sum(a * wel);
    if (l == 0) s_out[node] = sv;
  }
}

// one wave per node; lane = output dim. Edge weights computed in-kernel:
// lane-parallel col/s gather (coalesced), readlane broadcast, v gathers 8-deep.
__global__ __launch_bounds__(256) void k_aggr(const int* __restrict__ rs,
                                              const int* __restrict__ re,
                                              const int* __restrict__ col,
                                              const float* __restrict__ s,
                                              const float* __restrict__ be_p,
                                              const float* __restrict__ v,
                                              float* __restrict__ out, int n) {
  int gw = (int)((blockIdx.x * 256 + threadIdx.x) >> 6);
  int l = threadIdx.x & 63;
  if (gw >= n) return;
  int e0 = rs[gw], e1 = re[gw];
  float srow = s[gw];
  float be = be_p[0];
  float acc = 0.f, denom = 0.f;

  for (int base = e0; base < e1; base += 64) {
    int m = e1 - base;
    if (m > 64) m = 64;
    int c = 0;
    float w = 0.f;
    if (l < m) {
      c = col[base + l];
      w = __expf(fast_tanh(srow + s[c] + be));
    }
    denom += wave_sum(w);

    int j = 0;
    for (; j + 8 <= m; j += 8) {
      int c0 = __shfl(c, j), c1 = __shfl(c, j + 1), c2 = __shfl(c, j + 2), c3 = __shfl(c, j + 3);
      int c4 = __shfl(c, j + 4), c5 = __shfl(c, j + 5), c6 = __shfl(c, j + 6), c7 = __shfl(c, j + 7);
      float w0 = __shfl(w, j), w1 = __shfl(w, j + 1), w2 = __shfl(w, j + 2), w3 = __shfl(w, j + 3);
      float w4 = __shfl(w, j + 4), w5 = __shfl(w, j + 5), w6 = __shfl(w, j + 6), w7 = __shfl(w, j + 7);
      float v0 = v[(size_t)c0 * 64 + l];
      float v1 = v[(size_t)c1 * 64 + l];
      float v2 = v[(size_t)c2 * 64 + l];
      float v3 = v[(size_t)c3 * 64 + l];
      float v4 = v[(size_t)c4 * 64 + l];
      float v5 = v[(size_t)c5 * 64 + l];
      float v6 = v[(size_t)c6 * 64 + l];
      float v7 = v[(size_t)c7 * 64 + l];
      acc = fmaf(w0, v0, acc);
      acc = fmaf(w1, v1, acc);
      acc = fmaf(w2, v2, acc);
      acc = fmaf(w3, v3, acc);
      acc = fmaf(w4, v4, acc);
      acc = fmaf(w5, v5, acc);
      acc = fmaf(w6, v6, acc);
      acc = fmaf(w7, v7, acc);
    }
    for (; j + 4 <= m; j += 4) {
      int c0 = __shfl(c, j), c1 = __shfl(c, j + 1), c2 = __shfl(c, j + 2), c3 = __shfl(c, j + 3);
      float w0 = __shfl(w, j), w1 = __shfl(w, j + 1), w2 = __shfl(w, j + 2), w3 = __shfl(w, j + 3);
      float v0 = v[(size_t)c0 * 64 + l];
      float v1 = v[(size_t)c1 * 64 + l];
      float v2 = v[(size_t)c2 * 64 + l];
      float v3 = v[(size_t)c3 * 64 + l];
      acc = fmaf(w0, v0, acc);
      acc = fmaf(w1, v1, acc);
      acc = fmaf(w2, v2, acc);
      acc = fmaf(w3, v3, acc);
    }
    for (; j < m; j++) {
      int cj = __shfl(c, j);
      float wj = __shfl(w, j);
      acc = fmaf(wj, v[(size_t)cj * 64 + l], acc);
    }
  }

  float o = acc / denom;
  float sum = wave_sum(o);
  float sumsq = wave_sum(o * o);
  float var = (sumsq - sum * sum * (1.0f / 64.f)) * (1.0f / 63.f);
  out[(size_t)gw * 64 + l] = o / sqrtf(var);
}

extern "C" void kernel_launch(void* const* d_in, const int* in_sizes, int n_in,
                              void* d_out, int out_size, void* d_ws, size_t ws_size,
                              hipStream_t stream) {
  const float* h = (const float*)d_in[0];
  const int* ei = (const int*)d_in[1];
  const float* W11 = (const float*)d_in[2];
  const float* b11 = (const float*)d_in[3];
  const float* W12 = (const float*)d_in[4];  // [1,64] -> 64-vec
  const float* b12 = (const float*)d_in[5];
  const float* W13 = (const float*)d_in[6];
  const float* b13 = (const float*)d_in[7];
  const float* W21 = (const float*)d_in[8];
  const float* b21 = (const float*)d_in[9];
  const float* W22 = (const float*)d_in[10];
  const float* b22 = (const float*)d_in[11];
  const float* W23 = (const float*)d_in[12];
  const float* b23 = (const float*)d_in[13];

  const int N = in_sizes[0] / 128;  // 100000
  const int E = in_sizes[1] / 2;    // 1600000
  const int* src = ei;
  const int* dst = ei + E;
  const int NB = (N + BIN_NODES - 1) >> BIN_SHIFT;  // 782

  // workspace carve-up (~61 MB)
  char* p = (char*)d_ws;
  auto alloc = [&](size_t bytes) -> void* {
    void* r = (void*)p;
    p += (bytes + WS_ALIGN - 1) / WS_ALIGN * WS_ALIGN;
    return r;
  };
  int* cursor = (int*)alloc((size_t)NB * 4);
  int* binned = (int*)alloc((size_t)NB * BIN_CAP * 4);  // 8.0MB
  int* rsb = (int*)alloc((size_t)N * 4);
  int* reb = (int*)alloc((size_t)N * 4);
  float* sbuf = (float*)alloc((size_t)N * 4);
  float* vbuf = (float*)alloc((size_t)N * 64 * 4);
  float* out1 = (float*)alloc((size_t)N * 64 * 4);

  // ---- CSR build via bin sort (reused by both layers) ----
  k_init_cursor<<<(NB + 255) / 256, 256, 0, stream>>>(cursor, NB);
  k_bin<<<(E + EPB - 1) / EPB, 256, 0, stream>>>(src, dst, cursor, binned, E, NB);
  k_sort_bin<<<NB, 256, 0, stream>>>(binned, cursor, rsb, reb, N);

  // ---- layer 1 (K=128) ----
  k_node<128><<<(N + 31) / 32, 256, 0, stream>>>(h, W11, b11, W12, W13, b13, vbuf, sbuf, N);
  k_aggr<<<(N * 64 + 255) / 256, 256, 0, stream>>>(rsb, reb, binned, sbuf, b12, vbuf, out1, N);

  // ---- layer 2 (K=64) ----
  k_node<64><<<(N + 31) / 32, 256, 0, stream>>>(out1, W21, b21, W22, W23, b23, vbuf, sbuf, N);
  k_aggr<<<(N * 64 + 255) / 256, 256, 0, stream>>>(rsb, reb, binned, sbuf, b22, vbuf, (float*)d_out, N);
}

// Round 6
// 408.114 us; speedup vs baseline: 6.0450x; 2.5089x over previous
//
#include <hip/hip_runtime.h>

// GAT 2-layer, N=100000 nodes, E=1.6M edges, dims 128->64->64, all fp32.
// Strategy:
//   - s[i] = a[i]·we collapses edge-logit GEMV to per-node scalar (We is [1,64]).
//   - tanh-bounded logits => skip segment_max (exp ratio identical).
//   - CSR build WITHOUT write-amplified scatter: coarse 128-node-bin counting
//     sort (k_bin) then per-bin in-LDS sort (k_sort_bin) with fully coalesced
//     write-back of dst-only edges + per-node [rs,re).
//   - Aggregation: wave-per-node, lane-parallel col+s gather, shfl-broadcast
//     weights, 8-deep v-row gathers. No LDS atomics in hot loops (R4 lesson).
//   - k_node: x tile + W staged in LDS (coalesced float4), all-LDS inner loop.
//     kb loop capped at unroll 4: full unroll let the compiler hoist all 32
//     W-fragment reads -> ~200 VGPR demand vs 170 cap (launch_bounds 256,3)
//     -> 2.2GB/dispatch scratch spill traffic in the K=64 instantiation
//     (R3-R5 lesson: FETCH 791MB/WRITE 1.39GB signature was spill, not data).

#define WS_ALIGN 256
#define BIN_SHIFT 7
#define BIN_NODES 128
#define BIN_CAP 2560   // mean bin count 2048, sigma ~44 -> +11.6 sigma margin
#define MAX_BINS 1024
#define EPB 4096       // edges per k_bin block

__device__ __forceinline__ float wave_sum(float x) {
#pragma unroll
  for (int m = 32; m > 0; m >>= 1) x += __shfl_xor(x, m, 64);
  return x;
}

__device__ __forceinline__ float fast_tanh(float x) {
  x = fminf(15.f, fmaxf(-15.f, x));
  float e = __expf(2.f * x);
  return (e - 1.f) * __builtin_amdgcn_rcpf(e + 1.f);
}

__global__ void k_init_cursor(int* __restrict__ cursor, int nb) {
  int i = blockIdx.x * 256 + threadIdx.x;
  if (i < nb) cursor[i] = i * BIN_CAP;
}

// Coarse counting-sort of edges into 128-node bins. 4096 edges staged in LDS,
// per-block LDS histogram, ONE global atomic per (block,bin), packed 4B writes
// in ~5-entry runs per bin per block.
__global__ __launch_bounds__(256) void k_bin(const int* __restrict__ src,
                                             const int* __restrict__ dst,
                                             int* __restrict__ cursor,
                                             int* __restrict__ binned, int E, int nb) {
  __shared__ int ssrc[EPB];
  __shared__ int sdst[EPB];
  __shared__ int hist[MAX_BINS];
  __shared__ int base[MAX_BINS];
  int t = threadIdx.x;
  for (int i = t; i < nb; i += 256) hist[i] = 0;
  __syncthreads();
  int e0 = blockIdx.x * EPB;
  for (int i = t; i < EPB; i += 256) {
    int e = e0 + i;
    int sv = -1, dv = 0;
    if (e < E) {
      sv = src[e];
      dv = dst[e];
      atomicAdd(&hist[sv >> BIN_SHIFT], 1);
    }
    ssrc[i] = sv;
    sdst[i] = dv;
  }
  __syncthreads();
  for (int b = t; b < nb; b += 256) {
    int c = hist[b];
    base[b] = c ? atomicAdd(&cursor[b], c) : 0;
    hist[b] = 0;
  }
  __syncthreads();
  for (int i = t; i < EPB; i += 256) {
    int sv = ssrc[i];
    if (sv >= 0) {
      int b = sv >> BIN_SHIFT;
      int r = atomicAdd(&hist[b], 1);
      int pos = base[b] + r;
      if (pos < (b + 1) * BIN_CAP)  // overflow guard (never expected to fire)
        binned[pos] = (sdst[i] << BIN_SHIFT) | (sv & (BIN_NODES - 1));
    }
  }
}

// One block per bin: sort the bin's edges by src-within-bin in LDS, write back
// dst-only values fully coalesced, emit per-node [rs, re).
__global__ __launch_bounds__(256) void k_sort_bin(int* __restrict__ binned,
                                                  const int* __restrict__ cursor,
                                                  int* __restrict__ rs,
                                                  int* __restrict__ re, int n) {
  __shared__ int ents[BIN_CAP];
  __shared__ int sorted[BIN_CAP];
  __shared__ int hist[BIN_NODES];
  __shared__ int scan[BIN_NODES];
  __shared__ int cur[BIN_NODES];
  int bin = blockIdx.x;
  int t = threadIdx.x;
  int nbase = bin << BIN_SHIFT;
  int cnt = cursor[bin] - bin * BIN_CAP;
  if (cnt > BIN_CAP) cnt = BIN_CAP;
  if (t < BIN_NODES) hist[t] = 0;
  __syncthreads();
  int* bp = binned + (size_t)bin * BIN_CAP;
  for (int i = t; i < cnt; i += 256) {
    int pk = bp[i];
    ents[i] = pk;
    atomicAdd(&hist[pk & (BIN_NODES - 1)], 1);
  }
  __syncthreads();
  if (t < BIN_NODES) scan[t] = hist[t];
  __syncthreads();
  for (int off = 1; off < BIN_NODES; off <<= 1) {
    int add = (t < BIN_NODES && t >= off) ? scan[t - off] : 0;
    __syncthreads();
    if (t < BIN_NODES) scan[t] += add;
    __syncthreads();
  }
  if (t < BIN_NODES) {
    int ex = scan[t] - hist[t];  // exclusive
    cur[t] = ex;
    int node = nbase + t;
    if (node < n) {
      rs[node] = bin * BIN_CAP + ex;
      re[node] = bin * BIN_CAP + ex + hist[t];
    }
  }
  __syncthreads();
  for (int i = t; i < cnt; i += 256) {
    int pk = ents[i];
    int pos = atomicAdd(&cur[pk & (BIN_NODES - 1)], 1);
    sorted[pos] = pk >> BIN_SHIFT;  // keep dst only
  }
  __syncthreads();
  for (int i = t; i < cnt; i += 256) bp[i] = sorted[i];  // coalesced write-back
}

// Fused per-node kernel: v = tanh(x@Wv^T+bv) -> [N,64]; s = tanh(x@Wa^T+ba)·we -> [N].
// 4 waves/block, 8 nodes/wave (lane = output dim). x tile (32 rows x K) staged in
// LDS once via coalesced float4 loads; W staged per 64-K chunk, stride-66 padded.
// Requires n % 32 == 0 (true: 100000 = 3125*32).
template <int K>
__global__ __launch_bounds__(256, 3) void k_node(
    const float* __restrict__ x, const float* __restrict__ Wa, const float* __restrict__ ba,
    const float* __restrict__ we, const float* __restrict__ Wv, const float* __restrict__ bv,
    float* __restrict__ v_out, float* __restrict__ s_out, int n) {
  constexpr int KB = K / 4;   // float4 per x row
  constexpr int CH = K / 64;  // 64-wide K chunks
  __shared__ float4 sWa[16 * 66];  // [kb][o], stride 66: write 4-way, read free
  __shared__ float4 sWv[16 * 66];
  __shared__ float4 sx[32 * KB];
  int t = threadIdx.x;
  int l = t & 63;
  int w = t >> 6;
  int node0 = blockIdx.x * 32;

  const float4* xg = (const float4*)x + (size_t)node0 * KB;
#pragma unroll
  for (int i = 0; i < 32 * KB / 256; i++) sx[i * 256 + t] = xg[i * 256 + t];

  const float4* Wa4 = (const float4*)Wa;
  const float4* Wv4 = (const float4*)Wv;

  float acc_a[8], acc_v[8];
#pragma unroll
  for (int i = 0; i < 8; i++) { acc_a[i] = 0.f; acc_v[i] = 0.f; }

  const float4* xw = &sx[(w * 8) * KB];

  for (int ch = 0; ch < CH; ch++) {
    if (ch) __syncthreads();
    for (int f = t; f < 1024; f += 256) {
      int o = f >> 4, kb = f & 15;
      sWa[kb * 66 + o] = Wa4[o * KB + ch * 16 + kb];
      sWv[kb * 66 + o] = Wv4[o * KB + ch * 16 + kb];
    }
    __syncthreads();
    // unroll 4 (NOT full): full unroll hoists 32 W-fragment b128 reads ->
    // ~200 VGPR demand vs 170 cap -> scratch spills (the 2.2GB/dispatch bug).
#pragma unroll 4
    for (int kb = 0; kb < 16; kb++) {
      float4 wa = sWa[kb * 66 + l];
      float4 wv = sWv[kb * 66 + l];
#pragma unroll
      for (int i = 0; i < 8; i++) {
        float4 xv = xw[i * KB + ch * 16 + kb];  // broadcast ds_read_b128
        acc_a[i] = fmaf(xv.x, wa.x, fmaf(xv.y, wa.y, fmaf(xv.z, wa.z, fmaf(xv.w, wa.w, acc_a[i]))));
        acc_v[i] = fmaf(xv.x, wv.x, fmaf(xv.y, wv.y, fmaf(xv.z, wv.z, fmaf(xv.w, wv.w, acc_v[i]))));
      }
    }
  }

  float bal = ba[l], bvl = bv[l], wel = we[l];
#pragma unroll
  for (int i = 0; i < 8; i++) {
    int node = node0 + w * 8 + i;
    float a = fast_tanh(acc_a[i] + bal);
    float vv = fast_tanh(acc_v[i] + bvl);
    v_out[(size_t)node * 64 + l] = vv;
    float sv = wave_sum(a * wel);
    if (l == 0) s_out[node] = sv;
  }
}

// one wave per node; lane = output dim. Edge weights computed in-kernel:
// lane-parallel col/s gather (coalesced), readlane broadcast, v gathers 8-deep.
__global__ __launch_bounds__(256) void k_aggr(const int* __restrict__ rs,
                                              const int* __restrict__ re,
                                              const int* __restrict__ col,
                                              const float* __restrict__ s,
                                              const float* __restrict__ be_p,
                                              const float* __restrict__ v,
                                              float* __restrict__ out, int n) {
  int gw = (int)((blockIdx.x * 256 + threadIdx.x) >> 6);
  int l = threadIdx.x & 63;
  if (gw >= n) return;
  int e0 = rs[gw], e1 = re[gw];
  float srow = s[gw];
  float be = be_p[0];
  float acc = 0.f, denom = 0.f;

  for (int base = e0; base < e1; base += 64) {
    int m = e1 - base;
    if (m > 64) m = 64;
    int c = 0;
    float w = 0.f;
    if (l < m) {
      c = col[base + l];
      w = __expf(fast_tanh(srow + s[c] + be));
    }
    denom += wave_sum(w);

    int j = 0;
    for (; j + 8 <= m; j += 8) {
      int c0 = __shfl(c, j), c1 = __shfl(c, j + 1), c2 = __shfl(c, j + 2), c3 = __shfl(c, j + 3);
      int c4 = __shfl(c, j + 4), c5 = __shfl(c, j + 5), c6 = __shfl(c, j + 6), c7 = __shfl(c, j + 7);
      float w0 = __shfl(w, j), w1 = __shfl(w, j + 1), w2 = __shfl(w, j + 2), w3 = __shfl(w, j + 3);
      float w4 = __shfl(w, j + 4), w5 = __shfl(w, j + 5), w6 = __shfl(w, j + 6), w7 = __shfl(w, j + 7);
      float v0 = v[(size_t)c0 * 64 + l];
      float v1 = v[(size_t)c1 * 64 + l];
      float v2 = v[(size_t)c2 * 64 + l];
      float v3 = v[(size_t)c3 * 64 + l];
      float v4 = v[(size_t)c4 * 64 + l];
      float v5 = v[(size_t)c5 * 64 + l];
      float v6 = v[(size_t)c6 * 64 + l];
      float v7 = v[(size_t)c7 * 64 + l];
      acc = fmaf(w0, v0, acc);
      acc = fmaf(w1, v1, acc);
      acc = fmaf(w2, v2, acc);
      acc = fmaf(w3, v3, acc);
      acc = fmaf(w4, v4, acc);
      acc = fmaf(w5, v5, acc);
      acc = fmaf(w6, v6, acc);
      acc = fmaf(w7, v7, acc);
    }
    for (; j + 4 <= m; j += 4) {
      int c0 = __shfl(c, j), c1 = __shfl(c, j + 1), c2 = __shfl(c, j + 2), c3 = __shfl(c, j + 3);
      float w0 = __shfl(w, j), w1 = __shfl(w, j + 1), w2 = __shfl(w, j + 2), w3 = __shfl(w, j + 3);
      float v0 = v[(size_t)c0 * 64 + l];
      float v1 = v[(size_t)c1 * 64 + l];
      float v2 = v[(size_t)c2 * 64 + l];
      float v3 = v[(size_t)c3 * 64 + l];
      acc = fmaf(w0, v0, acc);
      acc = fmaf(w1, v1, acc);
      acc = fmaf(w2, v2, acc);
      acc = fmaf(w3, v3, acc);
    }
    for (; j < m; j++) {
      int cj = __shfl(c, j);
      float wj = __shfl(w, j);
      acc = fmaf(wj, v[(size_t)cj * 64 + l], acc);
    }
  }

  float o = acc / denom;
  float sum = wave_sum(o);
  float sumsq = wave_sum(o * o);
  float var = (sumsq - sum * sum * (1.0f / 64.f)) * (1.0f / 63.f);
  out[(size_t)gw * 64 + l] = o / sqrtf(var);
}

extern "C" void kernel_launch(void* const* d_in, const int* in_sizes, int n_in,
                              void* d_out, int out_size, void* d_ws, size_t ws_size,
                              hipStream_t stream) {
  const float* h = (const float*)d_in[0];
  const int* ei = (const int*)d_in[1];
  const float* W11 = (const float*)d_in[2];
  const float* b11 = (const float*)d_in[3];
  const float* W12 = (const float*)d_in[4];  // [1,64] -> 64-vec
  const float* b12 = (const float*)d_in[5];
  const float* W13 = (const float*)d_in[6];
  const float* b13 = (const float*)d_in[7];
  const float* W21 = (const float*)d_in[8];
  const float* b21 = (const float*)d_in[9];
  const float* W22 = (const float*)d_in[10];
  const float* b22 = (const float*)d_in[11];
  const float* W23 = (const float*)d_in[12];
  const float* b23 = (const float*)d_in[13];

  const int N = in_sizes[0] / 128;  // 100000
  const int E = in_sizes[1] / 2;    // 1600000
  const int* src = ei;
  const int* dst = ei + E;
  const int NB = (N + BIN_NODES - 1) >> BIN_SHIFT;  // 782

  // workspace carve-up (~61 MB)
  char* p = (char*)d_ws;
  auto alloc = [&](size_t bytes) -> void* {
    void* r = (void*)p;
    p += (bytes + WS_ALIGN - 1) / WS_ALIGN * WS_ALIGN;
    return r;
  };
  int* cursor = (int*)alloc((size_t)NB * 4);
  int* binned = (int*)alloc((size_t)NB * BIN_CAP * 4);  // 8.0MB
  int* rsb = (int*)alloc((size_t)N * 4);
  int* reb = (int*)alloc((size_t)N * 4);
  float* sbuf = (float*)alloc((size_t)N * 4);
  float* vbuf = (float*)alloc((size_t)N * 64 * 4);
  float* out1 = (float*)alloc((size_t)N * 64 * 4);

  // ---- CSR build via bin sort (reused by both layers) ----
  k_init_cursor<<<(NB + 255) / 256, 256, 0, stream>>>(cursor, NB);
  k_bin<<<(E + EPB - 1) / EPB, 256, 0, stream>>>(src, dst, cursor, binned, E, NB);
  k_sort_bin<<<NB, 256, 0, stream>>>(binned, cursor, rsb, reb, N);

  // ---- layer 1 (K=128) ----
  k_node<128><<<(N + 31) / 32, 256, 0, stream>>>(h, W11, b11, W12, W13, b13, vbuf, sbuf, N);
  k_aggr<<<(N * 64 + 255) / 256, 256, 0, stream>>>(rsb, reb, binned, sbuf, b12, vbuf, out1, N);

  // ---- layer 2 (K=64) ----
  k_node<64><<<(N + 31) / 32, 256, 0, stream>>>(out1, W21, b21, W22, W23, b23, vbuf, sbuf, N);
  k_aggr<<<(N * 64 + 255) / 256, 256, 0, stream>>>(rsb, reb, binned, sbuf, b22, vbuf, (float*)d_out, N);
}

// Round 7
// 379.011 us; speedup vs baseline: 6.5092x; 1.0768x over previous
//
#include <hip/hip_runtime.h>

// GAT 2-layer, N=100000 nodes, E=1.6M edges, dims 128->64->64, all fp32.
// Strategy:
//   - s[i] = a[i]·we collapses edge-logit GEMV to per-node scalar (We is [1,64]).
//   - tanh-bounded logits => skip segment_max (exp ratio identical).
//   - CSR build WITHOUT write-amplified scatter: coarse 128-node-bin counting
//     sort (k_bin) then per-bin in-LDS sort (k_sort_bin), coalesced write-back.
//   - Aggregation: wave-per-node, lane-parallel col+s gather, shfl-broadcast
//     weights, 8-deep v-row gathers. No LDS atomics in hot loops (R4 lesson).
//   - k_node v4 (MFMA): x@[Wa;Wv]^T as bf16 16x16x32 MFMA with hi/lo split
//     (xh*Wh + xh*Wl + xl*Wh => fp32-equivalent accuracy; dropped term ~2^-18).
//     No LDS/barriers; A-frags converted in-register from global, W-frags
//     pre-split to bf16 by k_prepw and L1/L2-resident. kblk loop unroll 1
//     (R3/R5 lesson: full unroll hoists all W frags -> VGPR spill storm).

#define WS_ALIGN 256
#define BIN_SHIFT 7
#define BIN_NODES 128
#define BIN_CAP 2560   // mean bin count 2048, sigma ~44 -> +11.6 sigma margin
#define MAX_BINS 1024
#define EPB 4096       // edges per k_bin block

typedef __attribute__((ext_vector_type(8))) short short8;
typedef __attribute__((ext_vector_type(4))) float f32x4;

__device__ __forceinline__ float wave_sum(float x) {
#pragma unroll
  for (int m = 32; m > 0; m >>= 1) x += __shfl_xor(x, m, 64);
  return x;
}

__device__ __forceinline__ float fast_tanh(float x) {
  x = fminf(15.f, fmaxf(-15.f, x));
  float e = __expf(2.f * x);
  return (e - 1.f) * __builtin_amdgcn_rcpf(e + 1.f);
}

__global__ void k_init_cursor(int* __restrict__ cursor, int nb) {
  int i = blockIdx.x * 256 + threadIdx.x;
  if (i < nb) cursor[i] = i * BIN_CAP;
}

// Coarse counting-sort of edges into 128-node bins.
__global__ __launch_bounds__(256) void k_bin(const int* __restrict__ src,
                                             const int* __restrict__ dst,
                                             int* __restrict__ cursor,
                                             int* __restrict__ binned, int E, int nb) {
  __shared__ int ssrc[EPB];
  __shared__ int sdst[EPB];
  __shared__ int hist[MAX_BINS];
  __shared__ int base[MAX_BINS];
  int t = threadIdx.x;
  for (int i = t; i < nb; i += 256) hist[i] = 0;
  __syncthreads();
  int e0 = blockIdx.x * EPB;
  for (int i = t; i < EPB; i += 256) {
    int e = e0 + i;
    int sv = -1, dv = 0;
    if (e < E) {
      sv = src[e];
      dv = dst[e];
      atomicAdd(&hist[sv >> BIN_SHIFT], 1);
    }
    ssrc[i] = sv;
    sdst[i] = dv;
  }
  __syncthreads();
  for (int b = t; b < nb; b += 256) {
    int c = hist[b];
    base[b] = c ? atomicAdd(&cursor[b], c) : 0;
    hist[b] = 0;
  }
  __syncthreads();
  for (int i = t; i < EPB; i += 256) {
    int sv = ssrc[i];
    if (sv >= 0) {
      int b = sv >> BIN_SHIFT;
      int r = atomicAdd(&hist[b], 1);
      int pos = base[b] + r;
      if (pos < (b + 1) * BIN_CAP)  // overflow guard (never expected to fire)
        binned[pos] = (sdst[i] << BIN_SHIFT) | (sv & (BIN_NODES - 1));
    }
  }
}

// One block per bin: sort by src-within-bin in LDS, coalesced write-back of
// dst-only values, emit per-node [rs, re).
__global__ __launch_bounds__(256) void k_sort_bin(int* __restrict__ binned,
                                                  const int* __restrict__ cursor,
                                                  int* __restrict__ rs,
                                                  int* __restrict__ re, int n) {
  __shared__ int ents[BIN_CAP];
  __shared__ int sorted[BIN_CAP];
  __shared__ int hist[BIN_NODES];
  __shared__ int scan[BIN_NODES];
  __shared__ int cur[BIN_NODES];
  int bin = blockIdx.x;
  int t = threadIdx.x;
  int nbase = bin << BIN_SHIFT;
  int cnt = cursor[bin] - bin * BIN_CAP;
  if (cnt > BIN_CAP) cnt = BIN_CAP;
  if (t < BIN_NODES) hist[t] = 0;
  __syncthreads();
  int* bp = binned + (size_t)bin * BIN_CAP;
  for (int i = t; i < cnt; i += 256) {
    int pk = bp[i];
    ents[i] = pk;
    atomicAdd(&hist[pk & (BIN_NODES - 1)], 1);
  }
  __syncthreads();
  if (t < BIN_NODES) scan[t] = hist[t];
  __syncthreads();
  for (int off = 1; off < BIN_NODES; off <<= 1) {
    int add = (t < BIN_NODES && t >= off) ? scan[t - off] : 0;
    __syncthreads();
    if (t < BIN_NODES) scan[t] += add;
    __syncthreads();
  }
  if (t < BIN_NODES) {
    int ex = scan[t] - hist[t];  // exclusive
    cur[t] = ex;
    int node = nbase + t;
    if (node < n) {
      rs[node] = bin * BIN_CAP + ex;
      re[node] = bin * BIN_CAP + ex + hist[t];
    }
  }
  __syncthreads();
  for (int i = t; i < cnt; i += 256) {
    int pk = ents[i];
    int pos = atomicAdd(&cur[pk & (BIN_NODES - 1)], 1);
    sorted[pos] = pk >> BIN_SHIFT;  // keep dst only
  }
  __syncthreads();
  for (int i = t; i < cnt; i += 256) bp[i] = sorted[i];  // coalesced write-back
}

// Split [Wa;Wv] (fp32, [64][K] each) into bf16 hi/lo, combined [128][K].
// hi = bit-truncation (lo compensates exactly), lo = bf16(x - hi).
__global__ void k_prepw(const float* __restrict__ Wa, const float* __restrict__ Wv,
                        short* __restrict__ Wh, short* __restrict__ Wl, int K) {
  int i = blockIdx.x * 256 + threadIdx.x;
  if (i >= 128 * K) return;
  int nrow = i / K, k = i - nrow * K;
  float f = (nrow < 64) ? Wa[nrow * K + k] : Wv[(nrow - 64) * K + k];
  unsigned u = __float_as_uint(f);
  float hf = __uint_as_float(u & 0xffff0000u);
  Wh[i] = (short)(u >> 16);
  Wl[i] = (short)(__float_as_uint(f - hf) >> 16);
}

// MFMA node kernel: D[node][0..127] = x[node][:] @ [Wa;Wv]^T via 16x16x32 bf16.
// Wave = 16 nodes, block = 64 nodes. A-frag: lane holds x[m=lane&15][q*8+j]
// (converted to bf16 hi/lo in-register). B-frag: lane holds W[n=lane&15][q*8+j].
// C/D: col=lane&15 (out dim), row=quad*4+reg (node). Epilogue fuses tanh and
// the s = tanh(a)·we cross-lane reduction.
template <int K>
__global__ __launch_bounds__(256) void k_node(
    const float* __restrict__ x, const short* __restrict__ Wh,
    const short* __restrict__ Wl, const float* __restrict__ ba,
    const float* __restrict__ we, const float* __restrict__ bv,
    float* __restrict__ v_out, float* __restrict__ s_out, int n) {
  constexpr int KBLK = K / 32;
  int t = threadIdx.x;
  int l = t & 63;
  int w = t >> 6;
  int q = l >> 4, c = l & 15;
  int node0w = blockIdx.x * 64 + w * 16;
  if (node0w >= n) return;

  int m = node0w + c;              // A row this lane supplies
  if (m >= n) m = n - 1;           // clamp (stores are guarded)
  const float* xr = x + (size_t)m * K + q * 8;

  f32x4 acc[8];
#pragma unroll
  for (int i = 0; i < 8; i++) acc[i] = (f32x4){0.f, 0.f, 0.f, 0.f};

#pragma unroll 1  // do NOT unroll: hoisting all W frags -> VGPR spill (R3/R5)
  for (int kb = 0; kb < KBLK; kb++) {
    // A fragment: 8 contiguous fp32 -> bf16 hi/lo in-register
    const float* xp = xr + kb * 32;
    float xv[8];
#pragma unroll
    for (int j = 0; j < 4; j++) xv[j] = xp[j];
#pragma unroll
    for (int j = 0; j < 4; j++) xv[4 + j] = xp[4 + j];
    short8 ah, al;
#pragma unroll
    for (int j = 0; j < 8; j++) {
      unsigned u = __float_as_uint(xv[j]);
      ah[j] = (short)(u >> 16);
      float hf = __uint_as_float(u & 0xffff0000u);
      al[j] = (short)(__float_as_uint(xv[j] - hf) >> 16);
    }
    int ko = kb * 32 + q * 8;
#pragma unroll
    for (int nt = 0; nt < 8; nt++) {
      const short* wph = Wh + (size_t)(nt * 16 + c) * K + ko;
      const short* wpl = Wl + (size_t)(nt * 16 + c) * K + ko;
      short8 wh = *(const short8*)wph;
      short8 wl = *(const short8*)wpl;
      acc[nt] = __builtin_amdgcn_mfma_f32_16x16x32_bf16(ah, wh, acc[nt], 0, 0, 0);
      acc[nt] = __builtin_amdgcn_mfma_f32_16x16x32_bf16(ah, wl, acc[nt], 0, 0, 0);
      acc[nt] = __builtin_amdgcn_mfma_f32_16x16x32_bf16(al, wh, acc[nt], 0, 0, 0);
    }
  }

  // ---- epilogue ----
  // s = sum_o tanh(a_o + ba_o) * we_o  (n-tiles 0..3 are the Wa half)
  float p[4] = {0.f, 0.f, 0.f, 0.f};
#pragma unroll
  for (int nt = 0; nt < 4; nt++) {
    int o = nt * 16 + c;
    float bav = ba[o], wev = we[o];
#pragma unroll
    for (int r = 0; r < 4; r++) p[r] += fast_tanh(acc[nt][r] + bav) * wev;
  }
#pragma unroll
  for (int mm = 1; mm < 16; mm <<= 1) {
#pragma unroll
    for (int r = 0; r < 4; r++) p[r] += __shfl_xor(p[r], mm, 64);
  }
  if (c == 0) {
#pragma unroll
    for (int r = 0; r < 4; r++) {
      int node = node0w + q * 4 + r;
      if (node < n) s_out[node] = p[r];
    }
  }
  // v = tanh(xWv^T + bv)  (n-tiles 4..7 are the Wv half)
#pragma unroll
  for (int nt = 4; nt < 8; nt++) {
    int o = (nt - 4) * 16 + c;
    float bvv = bv[o];
#pragma unroll
    for (int r = 0; r < 4; r++) {
      int node = node0w + q * 4 + r;
      if (node < n) v_out[(size_t)node * 64 + o] = fast_tanh(acc[nt][r] + bvv);
    }
  }
}

// one wave per node; lane = output dim. Edge weights computed in-kernel:
// lane-parallel col/s gather (coalesced), readlane broadcast, v gathers 8-deep.
__global__ __launch_bounds__(256) void k_aggr(const int* __restrict__ rs,
                                              const int* __restrict__ re,
                                              const int* __restrict__ col,
                                              const float* __restrict__ s,
                                              const float* __restrict__ be_p,
                                              const float* __restrict__ v,
                                              float* __restrict__ out, int n) {
  int gw = (int)((blockIdx.x * 256 + threadIdx.x) >> 6);
  int l = threadIdx.x & 63;
  if (gw >= n) return;
  int e0 = rs[gw], e1 = re[gw];
  float srow = s[gw];
  float be = be_p[0];
  float acc = 0.f, denom = 0.f;

  for (int base = e0; base < e1; base += 64) {
    int m = e1 - base;
    if (m > 64) m = 64;
    int c = 0;
    float w = 0.f;
    if (l < m) {
      c = col[base + l];
      w = __expf(fast_tanh(srow + s[c] + be));
    }
    denom += wave_sum(w);

    int j = 0;
    for (; j + 8 <= m; j += 8) {
      int c0 = __shfl(c, j), c1 = __shfl(c, j + 1), c2 = __shfl(c, j + 2), c3 = __shfl(c, j + 3);
      int c4 = __shfl(c, j + 4), c5 = __shfl(c, j + 5), c6 = __shfl(c, j + 6), c7 = __shfl(c, j + 7);
      float w0 = __shfl(w, j), w1 = __shfl(w, j + 1), w2 = __shfl(w, j + 2), w3 = __shfl(w, j + 3);
      float w4 = __shfl(w, j + 4), w5 = __shfl(w, j + 5), w6 = __shfl(w, j + 6), w7 = __shfl(w, j + 7);
      float v0 = v[(size_t)c0 * 64 + l];
      float v1 = v[(size_t)c1 * 64 + l];
      float v2 = v[(size_t)c2 * 64 + l];
      float v3 = v[(size_t)c3 * 64 + l];
      float v4 = v[(size_t)c4 * 64 + l];
      float v5 = v[(size_t)c5 * 64 + l];
      float v6 = v[(size_t)c6 * 64 + l];
      float v7 = v[(size_t)c7 * 64 + l];
      acc = fmaf(w0, v0, acc);
      acc = fmaf(w1, v1, acc);
      acc = fmaf(w2, v2, acc);
      acc = fmaf(w3, v3, acc);
      acc = fmaf(w4, v4, acc);
      acc = fmaf(w5, v5, acc);
      acc = fmaf(w6, v6, acc);
      acc = fmaf(w7, v7, acc);
    }
    for (; j + 4 <= m; j += 4) {
      int c0 = __shfl(c, j), c1 = __shfl(c, j + 1), c2 = __shfl(c, j + 2), c3 = __shfl(c, j + 3);
      float w0 = __shfl(w, j), w1 = __shfl(w, j + 1), w2 = __shfl(w, j + 2), w3 = __shfl(w, j + 3);
      float v0 = v[(size_t)c0 * 64 + l];
      float v1 = v[(size_t)c1 * 64 + l];
      float v2 = v[(size_t)c2 * 64 + l];
      float v3 = v[(size_t)c3 * 64 + l];
      acc = fmaf(w0, v0, acc);
      acc = fmaf(w1, v1, acc);
      acc = fmaf(w2, v2, acc);
      acc = fmaf(w3, v3, acc);
    }
    for (; j < m; j++) {
      int cj = __shfl(c, j);
      float wj = __shfl(w, j);
      acc = fmaf(wj, v[(size_t)cj * 64 + l], acc);
    }
  }

  float o = acc / denom;
  float sum = wave_sum(o);
  float sumsq = wave_sum(o * o);
  float var = (sumsq - sum * sum * (1.0f / 64.f)) * (1.0f / 63.f);
  out[(size_t)gw * 64 + l] = o / sqrtf(var);
}

extern "C" void kernel_launch(void* const* d_in, const int* in_sizes, int n_in,
                              void* d_out, int out_size, void* d_ws, size_t ws_size,
                              hipStream_t stream) {
  const float* h = (const float*)d_in[0];
  const int* ei = (const int*)d_in[1];
  const float* W11 = (const float*)d_in[2];
  const float* b11 = (const float*)d_in[3];
  const float* W12 = (const float*)d_in[4];  // [1,64] -> 64-vec
  const float* b12 = (const float*)d_in[5];
  const float* W13 = (const float*)d_in[6];
  const float* b13 = (const float*)d_in[7];
  const float* W21 = (const float*)d_in[8];
  const float* b21 = (const float*)d_in[9];
  const float* W22 = (const float*)d_in[10];
  const float* b22 = (const float*)d_in[11];
  const float* W23 = (const float*)d_in[12];
  const float* b23 = (const float*)d_in[13];

  const int N = in_sizes[0] / 128;  // 100000
  const int E = in_sizes[1] / 2;    // 1600000
  const int* src = ei;
  const int* dst = ei + E;
  const int NB = (N + BIN_NODES - 1) >> BIN_SHIFT;  // 782

  // workspace carve-up (~61 MB)
  char* p = (char*)d_ws;
  auto alloc = [&](size_t bytes) -> void* {
    void* r = (void*)p;
    p += (bytes + WS_ALIGN - 1) / WS_ALIGN * WS_ALIGN;
    return r;
  };
  int* cursor = (int*)alloc((size_t)NB * 4);
  int* binned = (int*)alloc((size_t)NB * BIN_CAP * 4);  // 8.0MB
  int* rsb = (int*)alloc((size_t)N * 4);
  int* reb = (int*)alloc((size_t)N * 4);
  float* sbuf = (float*)alloc((size_t)N * 4);
  float* vbuf = (float*)alloc((size_t)N * 64 * 4);
  float* out1 = (float*)alloc((size_t)N * 64 * 4);
  short* Wh1 = (short*)alloc(128 * 128 * 2);
  short* Wl1 = (short*)alloc(128 * 128 * 2);
  short* Wh2 = (short*)alloc(128 * 64 * 2);
  short* Wl2 = (short*)alloc(128 * 64 * 2);

  // ---- weight prep (bf16 hi/lo split) ----
  k_prepw<<<(128 * 128 + 255) / 256, 256, 0, stream>>>(W11, W13, Wh1, Wl1, 128);
  k_prepw<<<(128 * 64 + 255) / 256, 256, 0, stream>>>(W21, W23, Wh2, Wl2, 64);

  // ---- CSR build via bin sort (reused by both layers) ----
  k_init_cursor<<<(NB + 255) / 256, 256, 0, stream>>>(cursor, NB);
  k_bin<<<(E + EPB - 1) / EPB, 256, 0, stream>>>(src, dst, cursor, binned, E, NB);
  k_sort_bin<<<NB, 256, 0, stream>>>(binned, cursor, rsb, reb, N);

  // ---- layer 1 (K=128) ----
  k_node<128><<<(N + 63) / 64, 256, 0, stream>>>(h, Wh1, Wl1, b11, W12, b13, vbuf, sbuf, N);
  k_aggr<<<(N * 64 + 255) / 256, 256, 0, stream>>>(rsb, reb, binned, sbuf, b12, vbuf, out1, N);

  // ---- layer 2 (K=64) ----
  k_node<64><<<(N + 63) / 64, 256, 0, stream>>>(out1, Wh2, Wl2, b21, W22, b23, vbuf, sbuf, N);
  k_aggr<<<(N * 64 + 255) / 256, 256, 0, stream>>>(rsb, reb, binned, sbuf, b22, vbuf, (float*)d_out, N);
}

// Round 8
// 315.638 us; speedup vs baseline: 7.8161x; 1.2008x over previous
//
#include <hip/hip_runtime.h>

// GAT 2-layer, N=100000 nodes, E=1.6M edges, dims 128->64->64, all fp32.
// Strategy:
//   - s[i] = a[i]·we collapses edge-logit GEMV to per-node scalar (We is [1,64]).
//   - tanh-bounded logits => skip segment_max (exp ratio identical).
//   - CSR build: coarse 128-node-bin counting sort + per-bin in-LDS sort.
//   - Aggregation: wave-per-node, lane-parallel col+s gather, shfl-broadcast
//     weights, 8-deep v-row gathers; v stored in bf16 (halves gather bytes).
//   - k_node v5 (MFMA, transaction-aware): R7 lesson — per-lane strided frag
//     gathers shatter into ~16-32 L1 transactions each => latency/TA bound at
//     78us with MfmaUtil 4.6%. Fix: W pre-permuted to fragment-linear layout
//     (each B-frag = ONE coalesced 1KB wave load), A-frags via LDS-staged x
//     tile (padded rows, conflict-light ds_read_b128). hi/lo bf16 split keeps
//     fp32 accuracy (xh*Wh + xh*Wl + xl*Wh; dropped term ~2^-18).

#define WS_ALIGN 256
#define BIN_SHIFT 7
#define BIN_NODES 128
#define BIN_CAP 2560   // mean bin count 2048, sigma ~44 -> +11.6 sigma margin
#define MAX_BINS 1024
#define EPB 4096       // edges per k_bin block

typedef __attribute__((ext_vector_type(8))) short short8;
typedef __attribute__((ext_vector_type(4))) float f32x4;

__device__ __forceinline__ float wave_sum(float x) {
#pragma unroll
  for (int m = 32; m > 0; m >>= 1) x += __shfl_xor(x, m, 64);
  return x;
}

__device__ __forceinline__ float fast_tanh(float x) {
  x = fminf(15.f, fmaxf(-15.f, x));
  float e = __expf(2.f * x);
  return (e - 1.f) * __builtin_amdgcn_rcpf(e + 1.f);
}

__device__ __forceinline__ unsigned short f32_to_bf16_rne(float f) {
  unsigned u = __float_as_uint(f);
  unsigned r = u + 0x7fffu + ((u >> 16) & 1u);
  return (unsigned short)(r >> 16);
}

__device__ __forceinline__ float bf16_to_f32(unsigned short b) {
  return __uint_as_float(((unsigned)b) << 16);
}

__global__ void k_init_cursor(int* __restrict__ cursor, int nb) {
  int i = blockIdx.x * 256 + threadIdx.x;
  if (i < nb) cursor[i] = i * BIN_CAP;
}

// Coarse counting-sort of edges into 128-node bins.
__global__ __launch_bounds__(256) void k_bin(const int* __restrict__ src,
                                             const int* __restrict__ dst,
                                             int* __restrict__ cursor,
                                             int* __restrict__ binned, int E, int nb) {
  __shared__ int ssrc[EPB];
  __shared__ int sdst[EPB];
  __shared__ int hist[MAX_BINS];
  __shared__ int base[MAX_BINS];
  int t = threadIdx.x;
  for (int i = t; i < nb; i += 256) hist[i] = 0;
  __syncthreads();
  int e0 = blockIdx.x * EPB;
  for (int i = t; i < EPB; i += 256) {
    int e = e0 + i;
    int sv = -1, dv = 0;
    if (e < E) {
      sv = src[e];
      dv = dst[e];
      atomicAdd(&hist[sv >> BIN_SHIFT], 1);
    }
    ssrc[i] = sv;
    sdst[i] = dv;
  }
  __syncthreads();
  for (int b = t; b < nb; b += 256) {
    int c = hist[b];
    base[b] = c ? atomicAdd(&cursor[b], c) : 0;
    hist[b] = 0;
  }
  __syncthreads();
  for (int i = t; i < EPB; i += 256) {
    int sv = ssrc[i];
    if (sv >= 0) {
      int b = sv >> BIN_SHIFT;
      int r = atomicAdd(&hist[b], 1);
      int pos = base[b] + r;
      if (pos < (b + 1) * BIN_CAP)  // overflow guard (never expected to fire)
        binned[pos] = (sdst[i] << BIN_SHIFT) | (sv & (BIN_NODES - 1));
    }
  }
}

// One block per bin: sort by src-within-bin in LDS, coalesced write-back of
// dst-only values, emit per-node [rs, re).
__global__ __launch_bounds__(256) void k_sort_bin(int* __restrict__ binned,
                                                  const int* __restrict__ cursor,
                                                  int* __restrict__ rs,
                                                  int* __restrict__ re, int n) {
  __shared__ int ents[BIN_CAP];
  __shared__ int sorted[BIN_CAP];
  __shared__ int hist[BIN_NODES];
  __shared__ int scan[BIN_NODES];
  __shared__ int cur[BIN_NODES];
  int bin = blockIdx.x;
  int t = threadIdx.x;
  int nbase = bin << BIN_SHIFT;
  int cnt = cursor[bin] - bin * BIN_CAP;
  if (cnt > BIN_CAP) cnt = BIN_CAP;
  if (t < BIN_NODES) hist[t] = 0;
  __syncthreads();
  int* bp = binned + (size_t)bin * BIN_CAP;
  for (int i = t; i < cnt; i += 256) {
    int pk = bp[i];
    ents[i] = pk;
    atomicAdd(&hist[pk & (BIN_NODES - 1)], 1);
  }
  __syncthreads();
  if (t < BIN_NODES) scan[t] = hist[t];
  __syncthreads();
  for (int off = 1; off < BIN_NODES; off <<= 1) {
    int add = (t < BIN_NODES && t >= off) ? scan[t - off] : 0;
    __syncthreads();
    if (t < BIN_NODES) scan[t] += add;
    __syncthreads();
  }
  if (t < BIN_NODES) {
    int ex = scan[t] - hist[t];  // exclusive
    cur[t] = ex;
    int node = nbase + t;
    if (node < n) {
      rs[node] = bin * BIN_CAP + ex;
      re[node] = bin * BIN_CAP + ex + hist[t];
    }
  }
  __syncthreads();
  for (int i = t; i < cnt; i += 256) {
    int pk = ents[i];
    int pos = atomicAdd(&cur[pk & (BIN_NODES - 1)], 1);
    sorted[pos] = pk >> BIN_SHIFT;  // keep dst only
  }
  __syncthreads();
  for (int i = t; i < cnt; i += 256) bp[i] = sorted[i];  // coalesced write-back
}

// Split [Wa;Wv] into bf16 hi/lo in FRAGMENT-LINEAR layout: flat index
// i = (((nt*KBLK + kb)*4 + q)*16 + c)*8 + j  maps to W[nt*16+c][kb*32+q*8+j].
// A wave's B-frag load for (nt,kb) is then base + (nt*KBLK+kb)*1KB + lane*16B
// -> ONE coalesced 1KB load (R7 lesson: row-strided frag gathers shatter into
// ~16-32 L1 transactions each).
__global__ void k_prepw(const float* __restrict__ Wa, const float* __restrict__ Wv,
                        short* __restrict__ Wh, short* __restrict__ Wl, int K) {
  int i = blockIdx.x * 256 + threadIdx.x;
  if (i >= 128 * K) return;
  int KBLK = K / 32;
  int j = i & 7;
  int c = (i >> 3) & 15;
  int q = (i >> 7) & 3;
  int r = i >> 9;           // nt*KBLK + kb
  int nt = r / KBLK, kb = r - nt * KBLK;
  int row = nt * 16 + c;
  int col = kb * 32 + q * 8 + j;
  float f = (row < 64) ? Wa[row * K + col] : Wv[(row - 64) * K + col];
  unsigned u = __float_as_uint(f);
  float hf = __uint_as_float(u & 0xffff0000u);
  Wh[i] = (short)(u >> 16);
  Wl[i] = (short)(__float_as_uint(f - hf) >> 16);
}

// MFMA node kernel: D[node][0..127] = x[node][:] @ [Wa;Wv]^T via 16x16x32 bf16.
// Block = 64 nodes (4 waves x 16). x tile staged in LDS (padded rows); W frags
// fragment-linear in global (coalesced). C/D: col=lane&15, row=quad*4+reg.
// v output stored as bf16 (RNE) to halve k_aggr's gather bytes.
template <int K>
__global__ __launch_bounds__(256) void k_node(
    const float* __restrict__ x, const short* __restrict__ Wh,
    const short* __restrict__ Wl, const float* __restrict__ ba,
    const float* __restrict__ we, const float* __restrict__ bv,
    unsigned short* __restrict__ v_out, float* __restrict__ s_out, int n) {
  constexpr int KBLK = K / 32;
  constexpr int KP = K + 4;  // +4 floats: c-lanes land 4 banks apart (2-way, free)
  __shared__ float sx[64 * KP];
  int t = threadIdx.x;
  int l = t & 63;
  int w = t >> 6;
  int q = l >> 4, c = l & 15;
  int node0b = blockIdx.x * 64;

  // stage x tile coalesced (dense float4 rows -> padded LDS rows)
  {
    const float4* xg = (const float4*)(x + (size_t)node0b * K);
    constexpr int R4 = K / 4;  // float4 per row
#pragma unroll
    for (int it = 0; it < 64 * R4 / 256; it++) {
      int i = it * 256 + t;
      int r = i / R4, k4 = i - r * R4;
      float4 val = (node0b + r < n) ? xg[i] : (float4){0.f, 0.f, 0.f, 0.f};
      *(float4*)&sx[r * KP + k4 * 4] = val;
    }
  }
  __syncthreads();

  int node0w = node0b + w * 16;
  if (node0w >= n) return;  // safe: after the only barrier

  const short8* WhF = (const short8*)Wh;
  const short8* WlF = (const short8*)Wl;

  f32x4 acc[8];
#pragma unroll
  for (int i = 0; i < 8; i++) acc[i] = (f32x4){0.f, 0.f, 0.f, 0.f};

  const float* xl = sx + (w * 16 + c) * KP;

#pragma unroll 1  // do NOT unroll: hoisting all W frags -> VGPR spill (R3/R5)
  for (int kb = 0; kb < KBLK; kb++) {
    // A fragment from LDS: 8 contiguous fp32 -> bf16 hi/lo in-register
    float4 x0 = *(const float4*)&xl[kb * 32 + q * 8];
    float4 x1 = *(const float4*)&xl[kb * 32 + q * 8 + 4];
    float xv[8] = {x0.x, x0.y, x0.z, x0.w, x1.x, x1.y, x1.z, x1.w};
    short8 ah, al;
#pragma unroll
    for (int j = 0; j < 8; j++) {
      unsigned u = __float_as_uint(xv[j]);
      ah[j] = (short)(u >> 16);
      float hf = __uint_as_float(u & 0xffff0000u);
      al[j] = (short)(__float_as_uint(xv[j] - hf) >> 16);
    }
#pragma unroll
    for (int nt = 0; nt < 8; nt++) {
      short8 wh = WhF[(size_t)(nt * KBLK + kb) * 64 + l];  // coalesced 1KB
      short8 wl = WlF[(size_t)(nt * KBLK + kb) * 64 + l];
      acc[nt] = __builtin_amdgcn_mfma_f32_16x16x32_bf16(ah, wh, acc[nt], 0, 0, 0);
      acc[nt] = __builtin_amdgcn_mfma_f32_16x16x32_bf16(ah, wl, acc[nt], 0, 0, 0);
      acc[nt] = __builtin_amdgcn_mfma_f32_16x16x32_bf16(al, wh, acc[nt], 0, 0, 0);
    }
  }

  // ---- epilogue ----
  // s = sum_o tanh(a_o + ba_o) * we_o  (n-tiles 0..3 are the Wa half)
  float p[4] = {0.f, 0.f, 0.f, 0.f};
#pragma unroll
  for (int nt = 0; nt < 4; nt++) {
    int o = nt * 16 + c;
    float bav = ba[o], wev = we[o];
#pragma unroll
    for (int r = 0; r < 4; r++) p[r] += fast_tanh(acc[nt][r] + bav) * wev;
  }
#pragma unroll
  for (int mm = 1; mm < 16; mm <<= 1) {
#pragma unroll
    for (int r = 0; r < 4; r++) p[r] += __shfl_xor(p[r], mm, 64);
  }
  if (c == 0) {
#pragma unroll
    for (int r = 0; r < 4; r++) {
      int node = node0w + q * 4 + r;
      if (node < n) s_out[node] = p[r];
    }
  }
  // v = tanh(xWv^T + bv) -> bf16  (n-tiles 4..7 are the Wv half)
#pragma unroll
  for (int nt = 4; nt < 8; nt++) {
    int o = (nt - 4) * 16 + c;
    float bvv = bv[o];
#pragma unroll
    for (int r = 0; r < 4; r++) {
      int node = node0w + q * 4 + r;
      if (node < n)
        v_out[(size_t)node * 64 + o] = f32_to_bf16_rne(fast_tanh(acc[nt][r] + bvv));
    }
  }
}

// one wave per node; lane = output dim. Edge weights computed in-kernel:
// lane-parallel col/s gather (coalesced), readlane broadcast, v (bf16 rows,
// 128B) gathered 8-deep for MLP.
__global__ __launch_bounds__(256) void k_aggr(const int* __restrict__ rs,
                                              const int* __restrict__ re,
                                              const int* __restrict__ col,
                                              const float* __restrict__ s,
                                              const float* __restrict__ be_p,
                                              const unsigned short* __restrict__ v,
                                              float* __restrict__ out, int n) {
  int gw = (int)((blockIdx.x * 256 + threadIdx.x) >> 6);
  int l = threadIdx.x & 63;
  if (gw >= n) return;
  int e0 = rs[gw], e1 = re[gw];
  float srow = s[gw];
  float be = be_p[0];
  float acc = 0.f, denom = 0.f;

  for (int base = e0; base < e1; base += 64) {
    int m = e1 - base;
    if (m > 64) m = 64;
    int c = 0;
    float w = 0.f;
    if (l < m) {
      c = col[base + l];
      w = __expf(fast_tanh(srow + s[c] + be));
    }
    denom += wave_sum(w);

    int j = 0;
    for (; j + 8 <= m; j += 8) {
      int c0 = __shfl(c, j), c1 = __shfl(c, j + 1), c2 = __shfl(c, j + 2), c3 = __shfl(c, j + 3);
      int c4 = __shfl(c, j + 4), c5 = __shfl(c, j + 5), c6 = __shfl(c, j + 6), c7 = __shfl(c, j + 7);
      float w0 = __shfl(w, j), w1 = __shfl(w, j + 1), w2 = __shfl(w, j + 2), w3 = __shfl(w, j + 3);
      float w4 = __shfl(w, j + 4), w5 = __shfl(w, j + 5), w6 = __shfl(w, j + 6), w7 = __shfl(w, j + 7);
      float v0 = bf16_to_f32(v[(size_t)c0 * 64 + l]);
      float v1 = bf16_to_f32(v[(size_t)c1 * 64 + l]);
      float v2 = bf16_to_f32(v[(size_t)c2 * 64 + l]);
      float v3 = bf16_to_f32(v[(size_t)c3 * 64 + l]);
      float v4 = bf16_to_f32(v[(size_t)c4 * 64 + l]);
      float v5 = bf16_to_f32(v[(size_t)c5 * 64 + l]);
      float v6 = bf16_to_f32(v[(size_t)c6 * 64 + l]);
      float v7 = bf16_to_f32(v[(size_t)c7 * 64 + l]);
      acc = fmaf(w0, v0, acc);
      acc = fmaf(w1, v1, acc);
      acc = fmaf(w2, v2, acc);
      acc = fmaf(w3, v3, acc);
      acc = fmaf(w4, v4, acc);
      acc = fmaf(w5, v5, acc);
      acc = fmaf(w6, v6, acc);
      acc = fmaf(w7, v7, acc);
    }
    for (; j + 4 <= m; j += 4) {
      int c0 = __shfl(c, j), c1 = __shfl(c, j + 1), c2 = __shfl(c, j + 2), c3 = __shfl(c, j + 3);
      float w0 = __shfl(w, j), w1 = __shfl(w, j + 1), w2 = __shfl(w, j + 2), w3 = __shfl(w, j + 3);
      float v0 = bf16_to_f32(v[(size_t)c0 * 64 + l]);
      float v1 = bf16_to_f32(v[(size_t)c1 * 64 + l]);
      float v2 = bf16_to_f32(v[(size_t)c2 * 64 + l]);
      float v3 = bf16_to_f32(v[(size_t)c3 * 64 + l]);
      acc = fmaf(w0, v0, acc);
      acc = fmaf(w1, v1, acc);
      acc = fmaf(w2, v2, acc);
      acc = fmaf(w3, v3, acc);
    }
    for (; j < m; j++) {
      int cj = __shfl(c, j);
      float wj = __shfl(w, j);
      acc = fmaf(wj, bf16_to_f32(v[(size_t)cj * 64 + l]), acc);
    }
  }

  float o = acc / denom;
  float sum = wave_sum(o);
  float sumsq = wave_sum(o * o);
  float var = (sumsq - sum * sum * (1.0f / 64.f)) * (1.0f / 63.f);
  out[(size_t)gw * 64 + l] = o / sqrtf(var);
}

extern "C" void kernel_launch(void* const* d_in, const int* in_sizes, int n_in,
                              void* d_out, int out_size, void* d_ws, size_t ws_size,
                              hipStream_t stream) {
  const float* h = (const float*)d_in[0];
  const int* ei = (const int*)d_in[1];
  const float* W11 = (const float*)d_in[2];
  const float* b11 = (const float*)d_in[3];
  const float* W12 = (const float*)d_in[4];  // [1,64] -> 64-vec
  const float* b12 = (const float*)d_in[5];
  const float* W13 = (const float*)d_in[6];
  const float* b13 = (const float*)d_in[7];
  const float* W21 = (const float*)d_in[8];
  const float* b21 = (const float*)d_in[9];
  const float* W22 = (const float*)d_in[10];
  const float* b22 = (const float*)d_in[11];
  const float* W23 = (const float*)d_in[12];
  const float* b23 = (const float*)d_in[13];

  const int N = in_sizes[0] / 128;  // 100000
  const int E = in_sizes[1] / 2;    // 1600000
  const int* src = ei;
  const int* dst = ei + E;
  const int NB = (N + BIN_NODES - 1) >> BIN_SHIFT;  // 782

  // workspace carve-up (~48 MB)
  char* p = (char*)d_ws;
  auto alloc = [&](size_t bytes) -> void* {
    void* r = (void*)p;
    p += (bytes + WS_ALIGN - 1) / WS_ALIGN * WS_ALIGN;
    return r;
  };
  int* cursor = (int*)alloc((size_t)NB * 4);
  int* binned = (int*)alloc((size_t)NB * BIN_CAP * 4);  // 8.0MB
  int* rsb = (int*)alloc((size_t)N * 4);
  int* reb = (int*)alloc((size_t)N * 4);
  float* sbuf = (float*)alloc((size_t)N * 4);
  unsigned short* vbuf = (unsigned short*)alloc((size_t)N * 64 * 2);  // bf16
  float* out1 = (float*)alloc((size_t)N * 64 * 4);
  short* Wh1 = (short*)alloc(128 * 128 * 2);
  short* Wl1 = (short*)alloc(128 * 128 * 2);
  short* Wh2 = (short*)alloc(128 * 64 * 2);
  short* Wl2 = (short*)alloc(128 * 64 * 2);

  // ---- weight prep (bf16 hi/lo split, fragment-linear layout) ----
  k_prepw<<<(128 * 128 + 255) / 256, 256, 0, stream>>>(W11, W13, Wh1, Wl1, 128);
  k_prepw<<<(128 * 64 + 255) / 256, 256, 0, stream>>>(W21, W23, Wh2, Wl2, 64);

  // ---- CSR build via bin sort (reused by both layers) ----
  k_init_cursor<<<(NB + 255) / 256, 256, 0, stream>>>(cursor, NB);
  k_bin<<<(E + EPB - 1) / EPB, 256, 0, stream>>>(src, dst, cursor, binned, E, NB);
  k_sort_bin<<<NB, 256, 0, stream>>>(binned, cursor, rsb, reb, N);

  // ---- layer 1 (K=128) ----
  k_node<128><<<(N + 63) / 64, 256, 0, stream>>>(h, Wh1, Wl1, b11, W12, b13, vbuf, sbuf, N);
  k_aggr<<<(N * 64 + 255) / 256, 256, 0, stream>>>(rsb, reb, binned, sbuf, b12, vbuf, out1, N);

  // ---- layer 2 (K=64) ----
  k_node<64><<<(N + 63) / 64, 256, 0, stream>>>(out1, Wh2, Wl2, b21, W22, b23, vbuf, sbuf, N);
  k_aggr<<<(N * 64 + 255) / 256, 256, 0, stream>>>(rsb, reb, binned, sbuf, b22, vbuf, (float*)d_out, N);
}

// Round 9
// 303.675 us; speedup vs baseline: 8.1240x; 1.0394x over previous
//
#include <hip/hip_runtime.h>

// GAT 2-layer, N=100000 nodes, E=1.6M edges, dims 128->64->64, all fp32.
// Strategy:
//   - s[i] = a[i]·we collapses edge-logit GEMV to per-node scalar (We is [1,64]).
//   - tanh-bounded logits => skip segment_max (exp ratio identical).
//   - CSR build: coarse 128-node-bin counting sort + per-bin in-LDS sort.
//   - k_node (MFMA): W pre-permuted fragment-linear (one coalesced 1KB load
//     per B-frag, R7 lesson), A-frags via LDS-staged x tile; bf16 hi/lo split
//     keeps fp32 accuracy. v stored bf16 (halves gather bytes).
//   - k_aggr v3 (R8 lesson: VALU-issue-bound at 65% busy): 4 edges per gather
//     inst (lane=(edge-sub,dim-group), dwordx2 = 4 full rows/inst), tail-free
//     loop via w=0 guard lanes, butterfly cross-group reduce, rcp/rsq epilogue.

#define WS_ALIGN 256
#define BIN_SHIFT 7
#define BIN_NODES 128
#define BIN_CAP 2560   // mean bin count 2048, sigma ~44 -> +11.6 sigma margin
#define MAX_BINS 1024
#define EPB 4096       // edges per k_bin block

typedef __attribute__((ext_vector_type(8))) short short8;
typedef __attribute__((ext_vector_type(4))) float f32x4;

__device__ __forceinline__ float wave_sum(float x) {
#pragma unroll
  for (int m = 32; m > 0; m >>= 1) x += __shfl_xor(x, m, 64);
  return x;
}

__device__ __forceinline__ float fast_tanh(float x) {
  x = fminf(15.f, fmaxf(-15.f, x));
  float e = __expf(2.f * x);
  return (e - 1.f) * __builtin_amdgcn_rcpf(e + 1.f);
}

__device__ __forceinline__ unsigned short f32_to_bf16_rne(float f) {
  unsigned u = __float_as_uint(f);
  unsigned r = u + 0x7fffu + ((u >> 16) & 1u);
  return (unsigned short)(r >> 16);
}

// Split one element of [Wa;Wv] into bf16 hi/lo, FRAGMENT-LINEAR layout:
// i = (((nt*KBLK + kb)*4 + q)*16 + c)*8 + j  <->  W[nt*16+c][kb*32+q*8+j].
__device__ __forceinline__ void prepw_one(const float* __restrict__ Wa,
                                          const float* __restrict__ Wv,
                                          short* __restrict__ Wh, short* __restrict__ Wl,
                                          int K, int i) {
  int KBLK = K / 32;
  int j = i & 7;
  int c = (i >> 3) & 15;
  int q = (i >> 7) & 3;
  int r = i >> 9;  // nt*KBLK + kb
  int nt = r / KBLK, kb = r - nt * KBLK;
  int row = nt * 16 + c;
  int col = kb * 32 + q * 8 + j;
  float f = (row < 64) ? Wa[row * K + col] : Wv[(row - 64) * K + col];
  unsigned u = __float_as_uint(f);
  float hf = __uint_as_float(u & 0xffff0000u);
  Wh[i] = (short)(u >> 16);
  Wl[i] = (short)(__float_as_uint(f - hf) >> 16);
}

// Fused setup: weight prep for both layers + cursor init (one launch).
__global__ void k_setup(const float* __restrict__ W11, const float* __restrict__ W13,
                        short* __restrict__ Wh1, short* __restrict__ Wl1,
                        const float* __restrict__ W21, const float* __restrict__ W23,
                        short* __restrict__ Wh2, short* __restrict__ Wl2,
                        int* __restrict__ cursor, int nb) {
  int i = blockIdx.x * 256 + threadIdx.x;
  if (i < 16384) {
    prepw_one(W11, W13, Wh1, Wl1, 128, i);
  } else if (i < 16384 + 8192) {
    prepw_one(W21, W23, Wh2, Wl2, 64, i - 16384);
  } else {
    int b = i - 24576;
    if (b < nb) cursor[b] = b * BIN_CAP;
  }
}

// Coarse counting-sort of edges into 128-node bins.
__global__ __launch_bounds__(256) void k_bin(const int* __restrict__ src,
                                             const int* __restrict__ dst,
                                             int* __restrict__ cursor,
                                             int* __restrict__ binned, int E, int nb) {
  __shared__ int ssrc[EPB];
  __shared__ int sdst[EPB];
  __shared__ int hist[MAX_BINS];
  __shared__ int base[MAX_BINS];
  int t = threadIdx.x;
  for (int i = t; i < nb; i += 256) hist[i] = 0;
  __syncthreads();
  int e0 = blockIdx.x * EPB;
  for (int i = t; i < EPB; i += 256) {
    int e = e0 + i;
    int sv = -1, dv = 0;
    if (e < E) {
      sv = src[e];
      dv = dst[e];
      atomicAdd(&hist[sv >> BIN_SHIFT], 1);
    }
    ssrc[i] = sv;
    sdst[i] = dv;
  }
  __syncthreads();
  for (int b = t; b < nb; b += 256) {
    int c = hist[b];
    base[b] = c ? atomicAdd(&cursor[b], c) : 0;
    hist[b] = 0;
  }
  __syncthreads();
  for (int i = t; i < EPB; i += 256) {
    int sv = ssrc[i];
    if (sv >= 0) {
      int b = sv >> BIN_SHIFT;
      int r = atomicAdd(&hist[b], 1);
      int pos = base[b] + r;
      if (pos < (b + 1) * BIN_CAP)  // overflow guard (never expected to fire)
        binned[pos] = (sdst[i] << BIN_SHIFT) | (sv & (BIN_NODES - 1));
    }
  }
}

// One block per bin: sort by src-within-bin in LDS, coalesced write-back of
// dst-only values, emit per-node [rs, re).
__global__ __launch_bounds__(256) void k_sort_bin(int* __restrict__ binned,
                                                  const int* __restrict__ cursor,
                                                  int* __restrict__ rs,
                                                  int* __restrict__ re, int n) {
  __shared__ int ents[BIN_CAP];
  __shared__ int sorted[BIN_CAP];
  __shared__ int hist[BIN_NODES];
  __shared__ int scan[BIN_NODES];
  __shared__ int cur[BIN_NODES];
  int bin = blockIdx.x;
  int t = threadIdx.x;
  int nbase = bin << BIN_SHIFT;
  int cnt = cursor[bin] - bin * BIN_CAP;
  if (cnt > BIN_CAP) cnt = BIN_CAP;
  if (t < BIN_NODES) hist[t] = 0;
  __syncthreads();
  int* bp = binned + (size_t)bin * BIN_CAP;
  for (int i = t; i < cnt; i += 256) {
    int pk = bp[i];
    ents[i] = pk;
    atomicAdd(&hist[pk & (BIN_NODES - 1)], 1);
  }
  __syncthreads();
  if (t < BIN_NODES) scan[t] = hist[t];
  __syncthreads();
  for (int off = 1; off < BIN_NODES; off <<= 1) {
    int add = (t < BIN_NODES && t >= off) ? scan[t - off] : 0;
    __syncthreads();
    if (t < BIN_NODES) scan[t] += add;
    __syncthreads();
  }
  if (t < BIN_NODES) {
    int ex = scan[t] - hist[t];  // exclusive
    cur[t] = ex;
    int node = nbase + t;
    if (node < n) {
      rs[node] = bin * BIN_CAP + ex;
      re[node] = bin * BIN_CAP + ex + hist[t];
    }
  }
  __syncthreads();
  for (int i = t; i < cnt; i += 256) {
    int pk = ents[i];
    int pos = atomicAdd(&cur[pk & (BIN_NODES - 1)], 1);
    sorted[pos] = pk >> BIN_SHIFT;  // keep dst only
  }
  __syncthreads();
  for (int i = t; i < cnt; i += 256) bp[i] = sorted[i];  // coalesced write-back
}

// MFMA node kernel: D[node][0..127] = x[node][:] @ [Wa;Wv]^T via 16x16x32 bf16.
// Block = 64 nodes (4 waves x 16). x tile staged in LDS (padded rows); W frags
// fragment-linear in global (coalesced). C/D: col=lane&15, row=quad*4+reg.
// v output stored as bf16 (RNE) to halve k_aggr's gather bytes.
template <int K>
__global__ __launch_bounds__(256) void k_node(
    const float* __restrict__ x, const short* __restrict__ Wh,
    const short* __restrict__ Wl, const float* __restrict__ ba,
    const float* __restrict__ we, const float* __restrict__ bv,
    unsigned short* __restrict__ v_out, float* __restrict__ s_out, int n) {
  constexpr int KBLK = K / 32;
  constexpr int KP = K + 4;  // +4 floats: c-lanes land 4 banks apart (2-way, free)
  __shared__ float sx[64 * KP];
  int t = threadIdx.x;
  int l = t & 63;
  int w = t >> 6;
  int q = l >> 4, c = l & 15;
  int node0b = blockIdx.x * 64;

  // stage x tile coalesced (dense float4 rows -> padded LDS rows)
  {
    const float4* xg = (const float4*)(x + (size_t)node0b * K);
    constexpr int R4 = K / 4;  // float4 per row
#pragma unroll
    for (int it = 0; it < 64 * R4 / 256; it++) {
      int i = it * 256 + t;
      int r = i / R4, k4 = i - r * R4;
      float4 val = (node0b + r < n) ? xg[i] : (float4){0.f, 0.f, 0.f, 0.f};
      *(float4*)&sx[r * KP + k4 * 4] = val;
    }
  }
  __syncthreads();

  int node0w = node0b + w * 16;
  if (node0w >= n) return;  // safe: after the only barrier

  const short8* WhF = (const short8*)Wh;
  const short8* WlF = (const short8*)Wl;

  f32x4 acc[8];
#pragma unroll
  for (int i = 0; i < 8; i++) acc[i] = (f32x4){0.f, 0.f, 0.f, 0.f};

  const float* xl = sx + (w * 16 + c) * KP;

#pragma unroll 1  // do NOT unroll: hoisting all W frags -> VGPR spill (R3/R5)
  for (int kb = 0; kb < KBLK; kb++) {
    // A fragment from LDS: 8 contiguous fp32 -> bf16 hi/lo in-register
    float4 x0 = *(const float4*)&xl[kb * 32 + q * 8];
    float4 x1 = *(const float4*)&xl[kb * 32 + q * 8 + 4];
    float xv[8] = {x0.x, x0.y, x0.z, x0.w, x1.x, x1.y, x1.z, x1.w};
    short8 ah, al;
#pragma unroll
    for (int j = 0; j < 8; j++) {
      unsigned u = __float_as_uint(xv[j]);
      ah[j] = (short)(u >> 16);
      float hf = __uint_as_float(u & 0xffff0000u);
      al[j] = (short)(__float_as_uint(xv[j] - hf) >> 16);
    }
#pragma unroll
    for (int nt = 0; nt < 8; nt++) {
      short8 wh = WhF[(size_t)(nt * KBLK + kb) * 64 + l];  // coalesced 1KB
      short8 wl = WlF[(size_t)(nt * KBLK + kb) * 64 + l];
      acc[nt] = __builtin_amdgcn_mfma_f32_16x16x32_bf16(ah, wh, acc[nt], 0, 0, 0);
      acc[nt] = __builtin_amdgcn_mfma_f32_16x16x32_bf16(ah, wl, acc[nt], 0, 0, 0);
      acc[nt] = __builtin_amdgcn_mfma_f32_16x16x32_bf16(al, wh, acc[nt], 0, 0, 0);
    }
  }

  // ---- epilogue ----
  // s = sum_o tanh(a_o + ba_o) * we_o  (n-tiles 0..3 are the Wa half)
  float p[4] = {0.f, 0.f, 0.f, 0.f};
#pragma unroll
  for (int nt = 0; nt < 4; nt++) {
    int o = nt * 16 + c;
    float bav = ba[o], wev = we[o];
#pragma unroll
    for (int r = 0; r < 4; r++) p[r] += fast_tanh(acc[nt][r] + bav) * wev;
  }
#pragma unroll
  for (int mm = 1; mm < 16; mm <<= 1) {
#pragma unroll
    for (int r = 0; r < 4; r++) p[r] += __shfl_xor(p[r], mm, 64);
  }
  if (c == 0) {
#pragma unroll
    for (int r = 0; r < 4; r++) {
      int node = node0w + q * 4 + r;
      if (node < n) s_out[node] = p[r];
    }
  }
  // v = tanh(xWv^T + bv) -> bf16  (n-tiles 4..7 are the Wv half)
#pragma unroll
  for (int nt = 4; nt < 8; nt++) {
    int o = (nt - 4) * 16 + c;
    float bvv = bv[o];
#pragma unroll
    for (int r = 0; r < 4; r++) {
      int node = node0w + q * 4 + r;
      if (node < n)
        v_out[(size_t)node * 64 + o] = f32_to_bf16_rne(fast_tanh(acc[nt][r] + bvv));
    }
  }
}

// Wave per node. Lane = (edge-sub es=l>>4, dim-group g=l&15). Weights computed
// lane-parallel (one slot per edge, w=0 guard for slots >= m -> NO tail loops).
// Gather: each dwordx2 load fetches 4 full bf16 rows per instruction
// (16 lanes x 8B per row). Butterfly (xor 16,32) folds the 4 edge-sub partial
// sums; rcp/rsq epilogue; 16-lane float4 coalesced store.
__global__ __launch_bounds__(256) void k_aggr(const int* __restrict__ rs,
                                              const int* __restrict__ re,
                                              const int* __restrict__ col,
                                              const float* __restrict__ s,
                                              const float* __restrict__ be_p,
                                              const unsigned short* __restrict__ v,
                                              float* __restrict__ out, int n) {
  int gw = (int)((blockIdx.x * 256 + threadIdx.x) >> 6);
  int l = threadIdx.x & 63;
  if (gw >= n) return;
  int e0 = rs[gw], e1 = re[gw];
  float srow = s[gw];
  float be = be_p[0];
  int es = l >> 4;  // edge sub-slot 0..3
  int g = l & 15;   // dim group: dims g*4 .. g*4+3
  float a0 = 0.f, a1 = 0.f, a2 = 0.f, a3 = 0.f;
  float denom = 0.f;

  for (int base = e0; base < e1; base += 64) {
    int m = e1 - base;
    if (m > 64) m = 64;
    int c = 0;
    float w = 0.f;
    if (l < m) {
      c = col[base + l];
      w = __expf(fast_tanh(srow + s[c] + be));
    }
    denom += wave_sum(w);
    int iters = (m + 3) >> 2;
    for (int it = 0; it < iters; it++) {
      int j = (it << 2) + es;
      int cj = __shfl(c, j);    // bpermute: slots j>=m pull c=0,w=0 (harmless)
      float wj = __shfl(w, j);
      uint2 pk = *(const uint2*)(v + ((size_t)cj << 6) + (g << 2));
      a0 = fmaf(wj, __uint_as_float(pk.x << 16), a0);
      a1 = fmaf(wj, __uint_as_float(pk.x & 0xffff0000u), a1);
      a2 = fmaf(wj, __uint_as_float(pk.y << 16), a2);
      a3 = fmaf(wj, __uint_as_float(pk.y & 0xffff0000u), a3);
    }
  }

  // fold the 4 edge-sub partials (every lane ends with the full dim sums)
#pragma unroll
  for (int mm = 16; mm < 64; mm <<= 1) {
    a0 += __shfl_xor(a0, mm, 64);
    a1 += __shfl_xor(a1, mm, 64);
    a2 += __shfl_xor(a2, mm, 64);
    a3 += __shfl_xor(a3, mm, 64);
  }
  float inv = __builtin_amdgcn_rcpf(denom);
  float o0 = a0 * inv, o1 = a1 * inv, o2 = a2 * inv, o3 = a3 * inv;
  // row stats (each dim replicated 4x across the wave -> scale by 1/4)
  float ls = wave_sum(o0 + o1 + o2 + o3) * 0.25f;
  float lq = wave_sum(o0 * o0 + o1 * o1 + o2 * o2 + o3 * o3) * 0.25f;
  float var = (lq - ls * ls * (1.0f / 64.f)) * (1.0f / 63.f);
  float isd = __builtin_amdgcn_rsqf(var);
  if (es == 0) {
    float4 r = {o0 * isd, o1 * isd, o2 * isd, o3 * isd};
    *(float4*)&out[(size_t)gw * 64 + (g << 2)] = r;
  }
}

extern "C" void kernel_launch(void* const* d_in, const int* in_sizes, int n_in,
                              void* d_out, int out_size, void* d_ws, size_t ws_size,
                              hipStream_t stream) {
  const float* h = (const float*)d_in[0];
  const int* ei = (const int*)d_in[1];
  const float* W11 = (const float*)d_in[2];
  const float* b11 = (const float*)d_in[3];
  const float* W12 = (const float*)d_in[4];  // [1,64] -> 64-vec
  const float* b12 = (const float*)d_in[5];
  const float* W13 = (const float*)d_in[6];
  const float* b13 = (const float*)d_in[7];
  const float* W21 = (const float*)d_in[8];
  const float* b21 = (const float*)d_in[9];
  const float* W22 = (const float*)d_in[10];
  const float* b22 = (const float*)d_in[11];
  const float* W23 = (const float*)d_in[12];
  const float* b23 = (const float*)d_in[13];

  const int N = in_sizes[0] / 128;  // 100000
  const int E = in_sizes[1] / 2;    // 1600000
  const int* src = ei;
  const int* dst = ei + E;
  const int NB = (N + BIN_NODES - 1) >> BIN_SHIFT;  // 782

  // workspace carve-up (~48 MB)
  char* p = (char*)d_ws;
  auto alloc = [&](size_t bytes) -> void* {
    void* r = (void*)p;
    p += (bytes + WS_ALIGN - 1) / WS_ALIGN * WS_ALIGN;
    return r;
  };
  int* cursor = (int*)alloc((size_t)NB * 4);
  int* binned = (int*)alloc((size_t)NB * BIN_CAP * 4);  // 8.0MB
  int* rsb = (int*)alloc((size_t)N * 4);
  int* reb = (int*)alloc((size_t)N * 4);
  float* sbuf = (float*)alloc((size_t)N * 4);
  unsigned short* vbuf = (unsigned short*)alloc((size_t)N * 64 * 2);  // bf16
  float* out1 = (float*)alloc((size_t)N * 64 * 4);
  short* Wh1 = (short*)alloc(128 * 128 * 2);
  short* Wl1 = (short*)alloc(128 * 128 * 2);
  short* Wh2 = (short*)alloc(128 * 64 * 2);
  short* Wl2 = (short*)alloc(128 * 64 * 2);

  // ---- setup: weight prep (both layers) + cursor init, one launch ----
  k_setup<<<(24576 + NB + 255) / 256, 256, 0, stream>>>(
      W11, W13, Wh1, Wl1, W21, W23, Wh2, Wl2, cursor, NB);

  // ---- CSR build via bin sort (reused by both layers) ----
  k_bin<<<(E + EPB - 1) / EPB, 256, 0, stream>>>(src, dst, cursor, binned, E, NB);
  k_sort_bin<<<NB, 256, 0, stream>>>(binned, cursor, rsb, reb, N);

  // ---- layer 1 (K=128) ----
  k_node<128><<<(N + 63) / 64, 256, 0, stream>>>(h, Wh1, Wl1, b11, W12, b13, vbuf, sbuf, N);
  k_aggr<<<(N * 64 + 255) / 256, 256, 0, stream>>>(rsb, reb, binned, sbuf, b12, vbuf, out1, N);

  // ---- layer 2 (K=64) ----
  k_node<64><<<(N + 63) / 64, 256, 0, stream>>>(out1, Wh2, Wl2, b21, W22, b23, vbuf, sbuf, N);
  k_aggr<<<(N * 64 + 255) / 256, 256, 0, stream>>>(rsb, reb, binned, sbuf, b22, vbuf, (float*)d_out, N);
}